// Round 2
// baseline (2529.426 us; speedup 1.0000x reference)
//
#include <hip/hip_runtime.h>
#include <hip/hip_bf16.h>

typedef __hip_bfloat16 bf16;

// bf16 pair unpack helpers (little-endian: low 16 bits = element at lower address)
__device__ __forceinline__ float bflo(unsigned v){ union{unsigned u; float f;} c; c.u = v << 16; return c.f; }
__device__ __forceinline__ float bfhi(unsigned v){ union{unsigned u; float f;} c; c.u = v & 0xffff0000u; return c.f; }

// ---------------------------------------------------------------------------
// GEMM: C[M x NC] = A[M x K](bf16) @ B[K x NC](bf16)  (+ optional bias)
// BM=128, BN=64, BK=16, 256 threads, 8x4 outputs/thread, fp32 accumulate.
// OUT_BF16: store bf16 into Cb; else store f32 (+bias) into Cf.
// ---------------------------------------------------------------------------
template<bool OUT_BF16>
__global__ __launch_bounds__(256) void gemm_kernel(
    const bf16* __restrict__ A, const bf16* __restrict__ B,
    const bf16* __restrict__ bias,
    float* __restrict__ Cf, bf16* __restrict__ Cb,
    int M, int K, int NC)
{
  constexpr int BM = 128, BN = 64, BK = 16;
  __shared__ __align__(16) float As[BK][BM + 1];   // [kk][row], +1 pad breaks conflicts
  __shared__ __align__(16) float Bs[BK][BN + 4];   // [kk][col], row stride 272B (16B mult)
  const int tid  = threadIdx.x;
  const int tx   = tid & 15;        // 16 groups of 4 cols
  const int ty   = tid >> 4;        // 16 groups of 8 rows
  const int row0 = blockIdx.x * BM;
  const int col0 = blockIdx.y * BN;

  float acc[8][4];
  #pragma unroll
  for (int i = 0; i < 8; ++i)
    #pragma unroll
    for (int j = 0; j < 4; ++j) acc[i][j] = 0.f;

  for (int k0 = 0; k0 < K; k0 += BK) {
    // stage A tile: 128x16, each thread loads 8 contiguous bf16 (16B) along K
    {
      const int idx = tid * 8;
      const int r   = idx >> 4;          // tile row
      const int kk  = idx & 15;          // 0 or 8
      const int gr  = row0 + r;
      if (gr < M) {
        const uint4 v = *(const uint4*)(A + (size_t)gr * K + k0 + kk);
        const unsigned w[4] = {v.x, v.y, v.z, v.w};
        #pragma unroll
        for (int j = 0; j < 4; ++j) {
          As[kk + 2*j    ][r] = bflo(w[j]);
          As[kk + 2*j + 1][r] = bfhi(w[j]);
        }
      } else {
        #pragma unroll
        for (int j = 0; j < 8; ++j) As[kk + j][r] = 0.f;
      }
    }
    // stage B tile: 16x64, each thread loads 4 contiguous bf16 (8B)
    {
      const int idx = tid * 4;
      const int kk  = idx >> 6;
      const int c   = idx & 63;
      const uint2 v = *(const uint2*)(B + (size_t)(k0 + kk) * NC + col0 + c);
      Bs[kk][c    ] = bflo(v.x);
      Bs[kk][c + 1] = bfhi(v.x);
      Bs[kk][c + 2] = bflo(v.y);
      Bs[kk][c + 3] = bfhi(v.y);
    }
    __syncthreads();
    #pragma unroll
    for (int kk = 0; kk < BK; ++kk) {
      const float4 bv = *(const float4*)&Bs[kk][tx * 4];
      float a[8];
      #pragma unroll
      for (int i = 0; i < 8; ++i) a[i] = As[kk][ty * 8 + i];
      #pragma unroll
      for (int i = 0; i < 8; ++i) {
        acc[i][0] += a[i] * bv.x;
        acc[i][1] += a[i] * bv.y;
        acc[i][2] += a[i] * bv.z;
        acc[i][3] += a[i] * bv.w;
      }
    }
    __syncthreads();
  }

  float bb[4] = {0.f, 0.f, 0.f, 0.f};
  if (bias) {
    #pragma unroll
    for (int j = 0; j < 4; ++j) bb[j] = __bfloat162float(bias[col0 + tx*4 + j]);
  }
  #pragma unroll
  for (int i = 0; i < 8; ++i) {
    const int gr = row0 + ty * 8 + i;
    if (gr >= M) continue;
    const size_t off = (size_t)gr * NC + col0 + tx * 4;
    if (OUT_BF16) {
      __align__(8) bf16 tmp[4];
      #pragma unroll
      for (int j = 0; j < 4; ++j) tmp[j] = __float2bfloat16(acc[i][j]);
      *(uint2*)(Cb + off) = *(const uint2*)tmp;
    } else {
      float4 o;
      o.x = acc[i][0] + bb[0]; o.y = acc[i][1] + bb[1];
      o.z = acc[i][2] + bb[2]; o.w = acc[i][3] + bb[3];
      *(float4*)(Cf + off) = o;
    }
  }
}

// ---------------------------------------------------------------------------
// Edge kernel, block 0 (Cin=128). One wave (64 lanes) per edge.
// lane handles channels {2*lane, 2*lane+1} of the x-difference,
// and output channels {4*lane .. 4*lane+3} of the message.
// ---------------------------------------------------------------------------
__global__ __launch_bounds__(256) void edge0_kernel(
    const bf16* __restrict__ x, const int* __restrict__ ei,
    const bf16* __restrict__ u, const bf16* __restrict__ cvec,
    const bf16* __restrict__ y, float* __restrict__ s, float* __restrict__ cnt,
    int E)
{
  const int e = (int)(((unsigned)blockIdx.x * 256u + threadIdx.x) >> 6);
  if (e >= E) return;
  const int lane = threadIdx.x & 63;
  const int src = ei[e];
  const int dst = ei[E + e];

  const unsigned xs = ((const unsigned*)(x + (size_t)src * 128))[lane];
  const unsigned xd = ((const unsigned*)(x + (size_t)dst * 128))[lane];
  const float d0 = bflo(xs) - bflo(xd);
  const float d1 = bfhi(xs) - bfhi(xd);

  // u rows 2*lane and 2*lane+1 (4 heads each) = 8 bf16 = one 16B load
  const uint4 uv = *(const uint4*)(u + (size_t)lane * 8);
  float t0 = d0 * bflo(uv.x) + d1 * bflo(uv.z);
  float t1 = d0 * bfhi(uv.x) + d1 * bfhi(uv.z);
  float t2 = d0 * bflo(uv.y) + d1 * bflo(uv.w);
  float t3 = d0 * bfhi(uv.y) + d1 * bfhi(uv.w);
  #pragma unroll
  for (int off = 32; off > 0; off >>= 1) {
    t0 += __shfl_xor(t0, off);
    t1 += __shfl_xor(t1, off);
    t2 += __shfl_xor(t2, off);
    t3 += __shfl_xor(t3, off);
  }
  t0 += __bfloat162float(cvec[0]);
  t1 += __bfloat162float(cvec[1]);
  t2 += __bfloat162float(cvec[2]);
  t3 += __bfloat162float(cvec[3]);
  const float mx = fmaxf(fmaxf(t0, t1), fmaxf(t2, t3));
  const float e0 = __expf(t0 - mx), e1 = __expf(t1 - mx);
  const float e2 = __expf(t2 - mx), e3 = __expf(t3 - mx);
  const float inv = 1.f / (e0 + e1 + e2 + e3);
  const float q[4] = {e0 * inv, e1 * inv, e2 * inv, e3 * inv};

  const bf16* yb = y + (size_t)src * 1024 + lane * 4;
  float m0 = 0.f, m1 = 0.f, m2 = 0.f, m3 = 0.f;
  #pragma unroll
  for (int h = 0; h < 4; ++h) {
    const uint2 v = *(const uint2*)(yb + h * 256);
    m0 += q[h] * bflo(v.x); m1 += q[h] * bfhi(v.x);
    m2 += q[h] * bflo(v.y); m3 += q[h] * bfhi(v.y);
  }
  float* sp = s + (size_t)dst * 256 + lane * 4;
  atomicAdd(sp + 0, m0); atomicAdd(sp + 1, m1);
  atomicAdd(sp + 2, m2); atomicAdd(sp + 3, m3);
  if (lane == 0) atomicAdd(cnt + dst, 1.f);
}

// ---------------------------------------------------------------------------
// Edge kernel, block 1 (Cin=256). lane handles channels {4*lane..4*lane+3}.
// cnt is NOT accumulated (same graph as block 0 -> reuse).
// ---------------------------------------------------------------------------
__global__ __launch_bounds__(256) void edge1_kernel(
    const bf16* __restrict__ h0, const int* __restrict__ ei,
    const bf16* __restrict__ u, const bf16* __restrict__ cvec,
    const bf16* __restrict__ y, float* __restrict__ s,
    int E)
{
  const int e = (int)(((unsigned)blockIdx.x * 256u + threadIdx.x) >> 6);
  if (e >= E) return;
  const int lane = threadIdx.x & 63;
  const int src = ei[e];
  const int dst = ei[E + e];

  const uint2 hs = *(const uint2*)(h0 + (size_t)src * 256 + lane * 4);
  const uint2 hd = *(const uint2*)(h0 + (size_t)dst * 256 + lane * 4);
  const float d0 = bflo(hs.x) - bflo(hd.x);
  const float d1 = bfhi(hs.x) - bfhi(hd.x);
  const float d2 = bflo(hs.y) - bflo(hd.y);
  const float d3 = bfhi(hs.y) - bfhi(hd.y);

  // u rows 4*lane .. 4*lane+3 = 16 bf16 = 32B (two 16B loads)
  const uint4 ua = *(const uint4*)(u + (size_t)lane * 16);
  const uint4 ub = *(const uint4*)(u + (size_t)lane * 16 + 8);
  float t0 = d0*bflo(ua.x) + d1*bflo(ua.z) + d2*bflo(ub.x) + d3*bflo(ub.z);
  float t1 = d0*bfhi(ua.x) + d1*bfhi(ua.z) + d2*bfhi(ub.x) + d3*bfhi(ub.z);
  float t2 = d0*bflo(ua.y) + d1*bflo(ua.w) + d2*bflo(ub.y) + d3*bflo(ub.w);
  float t3 = d0*bfhi(ua.y) + d1*bfhi(ua.w) + d2*bfhi(ub.y) + d3*bfhi(ub.w);
  #pragma unroll
  for (int off = 32; off > 0; off >>= 1) {
    t0 += __shfl_xor(t0, off);
    t1 += __shfl_xor(t1, off);
    t2 += __shfl_xor(t2, off);
    t3 += __shfl_xor(t3, off);
  }
  t0 += __bfloat162float(cvec[0]);
  t1 += __bfloat162float(cvec[1]);
  t2 += __bfloat162float(cvec[2]);
  t3 += __bfloat162float(cvec[3]);
  const float mx = fmaxf(fmaxf(t0, t1), fmaxf(t2, t3));
  const float e0 = __expf(t0 - mx), e1 = __expf(t1 - mx);
  const float e2 = __expf(t2 - mx), e3 = __expf(t3 - mx);
  const float inv = 1.f / (e0 + e1 + e2 + e3);
  const float q[4] = {e0 * inv, e1 * inv, e2 * inv, e3 * inv};

  const bf16* yb = y + (size_t)src * 1024 + lane * 4;
  float m0 = 0.f, m1 = 0.f, m2 = 0.f, m3 = 0.f;
  #pragma unroll
  for (int h = 0; h < 4; ++h) {
    const uint2 v = *(const uint2*)(yb + h * 256);
    m0 += q[h] * bflo(v.x); m1 += q[h] * bfhi(v.x);
    m2 += q[h] * bflo(v.y); m3 += q[h] * bfhi(v.y);
  }
  float* sp = s + (size_t)dst * 256 + lane * 4;
  atomicAdd(sp + 0, m0); atomicAdd(sp + 1, m1);
  atomicAdd(sp + 2, m2); atomicAdd(sp + 3, m3);
}

// ---------------------------------------------------------------------------
// Finalize: out = relu((s + selfloop_msg)/(cnt+1) + bias + skip)
// selfloop: diff=0 -> q = softmax(c); msg = sum_h q_h * y[i,h,:]
// OUT_FLOAT: write float32 (final output, d_out); else bf16 (intermediate h0)
// ---------------------------------------------------------------------------
template<bool OUT_FLOAT>
__global__ __launch_bounds__(256) void finalize_kernel(
    const float* __restrict__ s, const float* __restrict__ cnt,
    const bf16* __restrict__ y, const bf16* __restrict__ cvec,
    const bf16* __restrict__ bias,
    const float* __restrict__ skipf, const bf16* __restrict__ skipb,
    float* __restrict__ outf, bf16* __restrict__ outb, int total)
{
  const int idx = (int)((unsigned)blockIdx.x * 256u + threadIdx.x);
  if (idx >= total) return;
  const int i = idx >> 8, k = idx & 255;
  const float c0 = __bfloat162float(cvec[0]), c1 = __bfloat162float(cvec[1]);
  const float c2 = __bfloat162float(cvec[2]), c3 = __bfloat162float(cvec[3]);
  const float mx = fmaxf(fmaxf(c0, c1), fmaxf(c2, c3));
  const float e0 = __expf(c0 - mx), e1 = __expf(c1 - mx);
  const float e2 = __expf(c2 - mx), e3 = __expf(c3 - mx);
  const float inv = 1.f / (e0 + e1 + e2 + e3);
  const bf16* yb = y + (size_t)i * 1024 + k;
  const float self = (e0 * __bfloat162float(yb[0])   + e1 * __bfloat162float(yb[256])
                    + e2 * __bfloat162float(yb[512]) + e3 * __bfloat162float(yb[768])) * inv;
  float v = (s[idx] + self) / (cnt[i] + 1.f) + __bfloat162float(bias[k]);
  v += skipf ? skipf[idx] : __bfloat162float(skipb[idx]);
  v = fmaxf(v, 0.f);
  if (OUT_FLOAT) outf[idx] = v;
  else           outb[idx] = __float2bfloat16(v);
}

// Output 1: edge_index values written as float32
__global__ __launch_bounds__(256) void edgecopy_kernel(
    const int* __restrict__ ei, float* __restrict__ out, int n)
{
  const int i = (int)((unsigned)blockIdx.x * 256u + threadIdx.x);
  if (i < n) out[i] = (float)ei[i];
}

extern "C" void kernel_launch(void* const* d_in, const int* in_sizes, int n_in,
                              void* d_out, int out_size, void* d_ws, size_t ws_size,
                              hipStream_t stream)
{
  const bf16* x   = (const bf16*)d_in[0];
  const int*  ei  = (const int*)d_in[1];
  const bf16* W0  = (const bf16*)d_in[2];
  const bf16* u0  = (const bf16*)d_in[3];
  const bf16* c0  = (const bf16*)d_in[4];
  const bf16* b0  = (const bf16*)d_in[5];
  const bf16* sW0 = (const bf16*)d_in[6];
  const bf16* sb0 = (const bf16*)d_in[7];
  const bf16* W1  = (const bf16*)d_in[8];
  const bf16* u1  = (const bf16*)d_in[9];
  const bf16* c1  = (const bf16*)d_in[10];
  const bf16* b1  = (const bf16*)d_in[11];

  const int N = in_sizes[0] / 128;   // 20000
  const int E = in_sizes[1] / 2;     // 320000

  // workspace layout (~92 MB)
  char* ws = (char*)d_ws;
  bf16*  y     = (bf16*)ws;  ws += (size_t)N * 1024 * sizeof(bf16);  // y0, then reused as y1
  float* skip0 = (float*)ws; ws += (size_t)N * 256 * sizeof(float);
  bf16*  h0    = (bf16*)ws;  ws += (size_t)N * 256 * sizeof(bf16);
  float* s     = (float*)ws; ws += (size_t)N * 256 * sizeof(float);
  float* cnt   = (float*)ws; ws += (size_t)N * sizeof(float);

  const size_t sBytes = (size_t)N * 256 * sizeof(float);
  hipMemsetAsync(s, 0, sBytes + (size_t)N * sizeof(float), stream);  // s + cnt

  const dim3 gY((N + 127) / 128, 1024 / 64);
  const dim3 gS((N + 127) / 128, 256 / 64);
  const int  ebBlocks = (E * 64 + 255) / 256;
  const int  fBlocks  = (N * 256 + 255) / 256;

  // ---- Block 0 ----
  gemm_kernel<true ><<<gY, 256, 0, stream>>>(x, W0,  nullptr, nullptr, y, N, 128, 1024);
  gemm_kernel<false><<<gS, 256, 0, stream>>>(x, sW0, sb0,     skip0,  nullptr, N, 128, 256);
  edge0_kernel<<<ebBlocks, 256, 0, stream>>>(x, ei, u0, c0, y, s, cnt, E);
  finalize_kernel<false><<<fBlocks, 256, 0, stream>>>(s, cnt, y, c0, b0, skip0, nullptr,
                                                      nullptr, h0, N * 256);

  // ---- Block 1 ----
  hipMemsetAsync(s, 0, sBytes, stream);
  gemm_kernel<true ><<<gY, 256, 0, stream>>>(h0, W1, nullptr, nullptr, y, N, 256, 1024);
  edge1_kernel<<<ebBlocks, 256, 0, stream>>>(h0, ei, u1, c1, y, s, E);
  finalize_kernel<true ><<<fBlocks, 256, 0, stream>>>(s, cnt, y, c1, b1, nullptr, h0,
                                                      (float*)d_out, nullptr, N * 256);

  // ---- Output 1: edge_index ----
  edgecopy_kernel<<<(2 * E + 255) / 256, 256, 0, stream>>>(
      ei, (float*)d_out + (size_t)N * 256, 2 * E);
}

// Round 3
// 711.035 us; speedup vs baseline: 3.5574x; 3.5574x over previous
//
#include <hip/hip_runtime.h>
#include <hip/hip_bf16.h>

typedef __hip_bfloat16 bf16;

__device__ __forceinline__ float bflo(unsigned v){ union{unsigned u; float f;} c; c.u = v << 16; return c.f; }
__device__ __forceinline__ float bfhi(unsigned v){ union{unsigned u; float f;} c; c.u = v & 0xffff0000u; return c.f; }

// ---------------------------------------------------------------------------
// GEMM: C[M x NC] = A[M x K](bf16) @ B[K x NC](bf16)  (+ optional bias)
// ---------------------------------------------------------------------------
template<bool OUT_BF16>
__global__ __launch_bounds__(256) void gemm_kernel(
    const bf16* __restrict__ A, const bf16* __restrict__ B,
    const bf16* __restrict__ bias,
    float* __restrict__ Cf, bf16* __restrict__ Cb,
    int M, int K, int NC)
{
  constexpr int BM = 128, BN = 64, BK = 16;
  __shared__ __align__(16) float As[BK][BM + 1];
  __shared__ __align__(16) float Bs[BK][BN + 4];
  const int tid  = threadIdx.x;
  const int tx   = tid & 15;
  const int ty   = tid >> 4;
  const int row0 = blockIdx.x * BM;
  const int col0 = blockIdx.y * BN;

  float acc[8][4];
  #pragma unroll
  for (int i = 0; i < 8; ++i)
    #pragma unroll
    for (int j = 0; j < 4; ++j) acc[i][j] = 0.f;

  for (int k0 = 0; k0 < K; k0 += BK) {
    {
      const int idx = tid * 8;
      const int r   = idx >> 4;
      const int kk  = idx & 15;
      const int gr  = row0 + r;
      if (gr < M) {
        const uint4 v = *(const uint4*)(A + (size_t)gr * K + k0 + kk);
        const unsigned w[4] = {v.x, v.y, v.z, v.w};
        #pragma unroll
        for (int j = 0; j < 4; ++j) {
          As[kk + 2*j    ][r] = bflo(w[j]);
          As[kk + 2*j + 1][r] = bfhi(w[j]);
        }
      } else {
        #pragma unroll
        for (int j = 0; j < 8; ++j) As[kk + j][r] = 0.f;
      }
    }
    {
      const int idx = tid * 4;
      const int kk  = idx >> 6;
      const int c   = idx & 63;
      const uint2 v = *(const uint2*)(B + (size_t)(k0 + kk) * NC + col0 + c);
      Bs[kk][c    ] = bflo(v.x);
      Bs[kk][c + 1] = bfhi(v.x);
      Bs[kk][c + 2] = bflo(v.y);
      Bs[kk][c + 3] = bfhi(v.y);
    }
    __syncthreads();
    #pragma unroll
    for (int kk = 0; kk < BK; ++kk) {
      const float4 bv = *(const float4*)&Bs[kk][tx * 4];
      float a[8];
      #pragma unroll
      for (int i = 0; i < 8; ++i) a[i] = As[kk][ty * 8 + i];
      #pragma unroll
      for (int i = 0; i < 8; ++i) {
        acc[i][0] += a[i] * bv.x;
        acc[i][1] += a[i] * bv.y;
        acc[i][2] += a[i] * bv.z;
        acc[i][3] += a[i] * bv.w;
      }
    }
    __syncthreads();
  }

  float bb[4] = {0.f, 0.f, 0.f, 0.f};
  if (bias) {
    #pragma unroll
    for (int j = 0; j < 4; ++j) bb[j] = __bfloat162float(bias[col0 + tx*4 + j]);
  }
  #pragma unroll
  for (int i = 0; i < 8; ++i) {
    const int gr = row0 + ty * 8 + i;
    if (gr >= M) continue;
    const size_t off = (size_t)gr * NC + col0 + tx * 4;
    if (OUT_BF16) {
      __align__(8) bf16 tmp[4];
      #pragma unroll
      for (int j = 0; j < 4; ++j) tmp[j] = __float2bfloat16(acc[i][j]);
      *(uint2*)(Cb + off) = *(const uint2*)tmp;
    } else {
      float4 o;
      o.x = acc[i][0] + bb[0]; o.y = acc[i][1] + bb[1];
      o.z = acc[i][2] + bb[2]; o.w = acc[i][3] + bb[3];
      *(float4*)(Cf + off) = o;
    }
  }
}

// ---------------------------------------------------------------------------
// Edge sorting by dst: histogram -> single-block scan -> scatter
// ---------------------------------------------------------------------------
__global__ __launch_bounds__(256) void hist_kernel(
    const int* __restrict__ ei, int* __restrict__ deg, int E)
{
  const int e = (int)((unsigned)blockIdx.x * 256u + threadIdx.x);
  if (e < E) atomicAdd(deg + ei[E + e], 1);
}

__global__ __launch_bounds__(256) void scan_kernel(
    const int* __restrict__ deg, int* __restrict__ rowptr, int N)
{
  __shared__ int part[256];
  const int t = threadIdx.x;
  const int chunk = (N + 255) / 256;
  const int start = t * chunk;
  const int stop  = min(start + chunk, N);
  int sum = 0;
  for (int j = start; j < stop; ++j) sum += deg[j];
  part[t] = sum;
  __syncthreads();
  // inclusive Hillis-Steele scan over 256 partials
  for (int off = 1; off < 256; off <<= 1) {
    int v = (t >= off) ? part[t - off] : 0;
    __syncthreads();
    part[t] += v;
    __syncthreads();
  }
  int base = (t == 0) ? 0 : part[t - 1];
  for (int j = start; j < stop; ++j) { rowptr[j] = base; base += deg[j]; }
  if (t == 255) rowptr[N] = part[255];
}

__global__ __launch_bounds__(256) void scatter_kernel(
    const int* __restrict__ ei, const int* __restrict__ rowptr,
    int* __restrict__ cursor, int* __restrict__ ssrc, int* __restrict__ sdst, int E)
{
  const int e = (int)((unsigned)blockIdx.x * 256u + threadIdx.x);
  if (e >= E) return;
  const int src = ei[e];
  const int d   = ei[E + e];
  const int p   = rowptr[d] + atomicAdd(cursor + d, 1);
  ssrc[p] = src;
  sdst[p] = d;
}

// ---------------------------------------------------------------------------
// Pass A: per sorted edge, compute softmax attention q[e][4]. One wave/edge.
// Cin=128 variant (x), lane owns 2 channels.
// ---------------------------------------------------------------------------
__global__ __launch_bounds__(256) void passA0_kernel(
    const bf16* __restrict__ x, const int* __restrict__ ssrc,
    const int* __restrict__ sdst,
    const bf16* __restrict__ u, const bf16* __restrict__ cvec,
    float4* __restrict__ qs, int E)
{
  const int e = (int)(((unsigned)blockIdx.x * 256u + threadIdx.x) >> 6);
  if (e >= E) return;
  const int lane = threadIdx.x & 63;
  const int src = ssrc[e];
  const int dst = sdst[e];

  const unsigned xs = ((const unsigned*)(x + (size_t)src * 128))[lane];
  const unsigned xd = ((const unsigned*)(x + (size_t)dst * 128))[lane];
  const float d0 = bflo(xs) - bflo(xd);
  const float d1 = bfhi(xs) - bfhi(xd);

  const uint4 uv = *(const uint4*)(u + (size_t)lane * 8);
  float t0 = d0 * bflo(uv.x) + d1 * bflo(uv.z);
  float t1 = d0 * bfhi(uv.x) + d1 * bfhi(uv.z);
  float t2 = d0 * bflo(uv.y) + d1 * bflo(uv.w);
  float t3 = d0 * bfhi(uv.y) + d1 * bfhi(uv.w);
  #pragma unroll
  for (int off = 32; off > 0; off >>= 1) {
    t0 += __shfl_xor(t0, off);
    t1 += __shfl_xor(t1, off);
    t2 += __shfl_xor(t2, off);
    t3 += __shfl_xor(t3, off);
  }
  if (lane == 0) {
    t0 += __bfloat162float(cvec[0]);
    t1 += __bfloat162float(cvec[1]);
    t2 += __bfloat162float(cvec[2]);
    t3 += __bfloat162float(cvec[3]);
    const float mx = fmaxf(fmaxf(t0, t1), fmaxf(t2, t3));
    const float e0 = __expf(t0 - mx), e1 = __expf(t1 - mx);
    const float e2 = __expf(t2 - mx), e3 = __expf(t3 - mx);
    const float inv = 1.f / (e0 + e1 + e2 + e3);
    qs[e] = make_float4(e0 * inv, e1 * inv, e2 * inv, e3 * inv);
  }
}

// Cin=256 variant (h0), lane owns 4 channels.
__global__ __launch_bounds__(256) void passA1_kernel(
    const bf16* __restrict__ h0, const int* __restrict__ ssrc,
    const int* __restrict__ sdst,
    const bf16* __restrict__ u, const bf16* __restrict__ cvec,
    float4* __restrict__ qs, int E)
{
  const int e = (int)(((unsigned)blockIdx.x * 256u + threadIdx.x) >> 6);
  if (e >= E) return;
  const int lane = threadIdx.x & 63;
  const int src = ssrc[e];
  const int dst = sdst[e];

  const uint2 hs = *(const uint2*)(h0 + (size_t)src * 256 + lane * 4);
  const uint2 hd = *(const uint2*)(h0 + (size_t)dst * 256 + lane * 4);
  const float d0 = bflo(hs.x) - bflo(hd.x);
  const float d1 = bfhi(hs.x) - bfhi(hd.x);
  const float d2 = bflo(hs.y) - bflo(hd.y);
  const float d3 = bfhi(hs.y) - bfhi(hd.y);

  const uint4 ua = *(const uint4*)(u + (size_t)lane * 16);
  const uint4 ub = *(const uint4*)(u + (size_t)lane * 16 + 8);
  float t0 = d0*bflo(ua.x) + d1*bflo(ua.z) + d2*bflo(ub.x) + d3*bflo(ub.z);
  float t1 = d0*bfhi(ua.x) + d1*bfhi(ua.z) + d2*bfhi(ub.x) + d3*bfhi(ub.z);
  float t2 = d0*bflo(ua.y) + d1*bflo(ua.w) + d2*bflo(ub.y) + d3*bflo(ub.w);
  float t3 = d0*bfhi(ua.y) + d1*bfhi(ua.w) + d2*bfhi(ub.y) + d3*bfhi(ub.w);
  #pragma unroll
  for (int off = 32; off > 0; off >>= 1) {
    t0 += __shfl_xor(t0, off);
    t1 += __shfl_xor(t1, off);
    t2 += __shfl_xor(t2, off);
    t3 += __shfl_xor(t3, off);
  }
  if (lane == 0) {
    t0 += __bfloat162float(cvec[0]);
    t1 += __bfloat162float(cvec[1]);
    t2 += __bfloat162float(cvec[2]);
    t3 += __bfloat162float(cvec[3]);
    const float mx = fmaxf(fmaxf(t0, t1), fmaxf(t2, t3));
    const float e0 = __expf(t0 - mx), e1 = __expf(t1 - mx);
    const float e2 = __expf(t2 - mx), e3 = __expf(t3 - mx);
    const float inv = 1.f / (e0 + e1 + e2 + e3);
    qs[e] = make_float4(e0 * inv, e1 * inv, e2 * inv, e3 * inv);
  }
}

// ---------------------------------------------------------------------------
// Pass B: one block per dst node, thread = output channel. Gathers the node's
// sorted edge segment, accumulates q-weighted head blend of y[src], fuses the
// self-loop, mean, bias, skip and ReLU. No atomics.
// OUT_FLOAT: write float (d_out). SKIP_FLOAT: skip comes from float buffer.
// ---------------------------------------------------------------------------
template<bool OUT_FLOAT, bool SKIP_FLOAT>
__global__ __launch_bounds__(256) void passB_kernel(
    const int* __restrict__ rowptr, const int* __restrict__ ssrc,
    const float4* __restrict__ qs, const bf16* __restrict__ y,
    const bf16* __restrict__ cvec, const bf16* __restrict__ bias,
    const float* __restrict__ skipf, const bf16* __restrict__ skipb,
    float* __restrict__ outf, bf16* __restrict__ outb)
{
  const int i = blockIdx.x;
  const int k = threadIdx.x;
  const int beg = rowptr[i], end = rowptr[i + 1];

  float acc = 0.f;
  for (int e = beg; e < end; ++e) {
    const int src = ssrc[e];              // wave-uniform
    const float4 q = qs[e];               // wave-uniform broadcast
    const bf16* yb = y + (size_t)src * 1024 + k;
    acc += q.x * __bfloat162float(yb[0])
         + q.y * __bfloat162float(yb[256])
         + q.z * __bfloat162float(yb[512])
         + q.w * __bfloat162float(yb[768]);
  }

  // self loop: q = softmax(c)
  const float c0 = __bfloat162float(cvec[0]), c1 = __bfloat162float(cvec[1]);
  const float c2 = __bfloat162float(cvec[2]), c3 = __bfloat162float(cvec[3]);
  const float mx = fmaxf(fmaxf(c0, c1), fmaxf(c2, c3));
  const float e0 = __expf(c0 - mx), e1 = __expf(c1 - mx);
  const float e2 = __expf(c2 - mx), e3 = __expf(c3 - mx);
  const float inv = 1.f / (e0 + e1 + e2 + e3);
  const bf16* yi = y + (size_t)i * 1024 + k;
  acc += (e0 * __bfloat162float(yi[0])   + e1 * __bfloat162float(yi[256])
        + e2 * __bfloat162float(yi[512]) + e3 * __bfloat162float(yi[768])) * inv;

  const int idx = i * 256 + k;
  float v = acc / (float)(end - beg + 1) + __bfloat162float(bias[k]);
  v += SKIP_FLOAT ? skipf[idx] : __bfloat162float(skipb[idx]);
  v = fmaxf(v, 0.f);
  if (OUT_FLOAT) outf[idx] = v;
  else           outb[idx] = __float2bfloat16(v);
}

// Output 1: edge_index values written as float32
__global__ __launch_bounds__(256) void edgecopy_kernel(
    const int* __restrict__ ei, float* __restrict__ out, int n)
{
  const int i = (int)((unsigned)blockIdx.x * 256u + threadIdx.x);
  if (i < n) out[i] = (float)ei[i];
}

extern "C" void kernel_launch(void* const* d_in, const int* in_sizes, int n_in,
                              void* d_out, int out_size, void* d_ws, size_t ws_size,
                              hipStream_t stream)
{
  const bf16* x   = (const bf16*)d_in[0];
  const int*  ei  = (const int*)d_in[1];
  const bf16* W0  = (const bf16*)d_in[2];
  const bf16* u0  = (const bf16*)d_in[3];
  const bf16* c0  = (const bf16*)d_in[4];
  const bf16* b0  = (const bf16*)d_in[5];
  const bf16* sW0 = (const bf16*)d_in[6];
  const bf16* sb0 = (const bf16*)d_in[7];
  const bf16* W1  = (const bf16*)d_in[8];
  const bf16* u1  = (const bf16*)d_in[9];
  const bf16* c1  = (const bf16*)d_in[10];
  const bf16* b1  = (const bf16*)d_in[11];

  const int N = in_sizes[0] / 128;   // 20000
  const int E = in_sizes[1] / 2;     // 320000

  // workspace layout (~80 MB)
  char* ws = (char*)d_ws;
  bf16*   y      = (bf16*)ws;   ws += (size_t)N * 1024 * sizeof(bf16);
  float*  skip0  = (float*)ws;  ws += (size_t)N * 256 * sizeof(float);
  bf16*   h0     = (bf16*)ws;   ws += (size_t)N * 256 * sizeof(bf16);
  float4* qs     = (float4*)ws; ws += (size_t)E * sizeof(float4);
  int*    ssrc   = (int*)ws;    ws += (size_t)E * sizeof(int);
  int*    sdst   = (int*)ws;    ws += (size_t)E * sizeof(int);
  int*    deg    = (int*)ws;    ws += (size_t)N * sizeof(int);
  int*    cursor = (int*)ws;    ws += (size_t)N * sizeof(int);
  int*    rowptr = (int*)ws;    ws += ((size_t)N + 1) * sizeof(int);

  hipMemsetAsync(deg, 0, 2 * (size_t)N * sizeof(int), stream);  // deg + cursor

  const dim3 gY((N + 127) / 128, 1024 / 64);
  const dim3 gS((N + 127) / 128, 256 / 64);
  const int  eBlocks  = (E + 255) / 256;
  const int  ewBlocks = (E * 64 + 255) / 256;   // wave-per-edge kernels

  // ---- sort edges by dst (reused by both blocks) ----
  hist_kernel<<<eBlocks, 256, 0, stream>>>(ei, deg, E);
  scan_kernel<<<1, 256, 0, stream>>>(deg, rowptr, N);
  scatter_kernel<<<eBlocks, 256, 0, stream>>>(ei, rowptr, cursor, ssrc, sdst, E);

  // ---- Block 0 ----
  gemm_kernel<true ><<<gY, 256, 0, stream>>>(x, W0,  nullptr, nullptr, y, N, 128, 1024);
  gemm_kernel<false><<<gS, 256, 0, stream>>>(x, sW0, sb0,     skip0,  nullptr, N, 128, 256);
  passA0_kernel<<<ewBlocks, 256, 0, stream>>>(x, ssrc, sdst, u0, c0, qs, E);
  passB_kernel<false, true><<<N, 256, 0, stream>>>(rowptr, ssrc, qs, y, c0, b0,
                                                   skip0, nullptr, nullptr, h0);

  // ---- Block 1 ----
  gemm_kernel<true ><<<gY, 256, 0, stream>>>(h0, W1, nullptr, nullptr, y, N, 256, 1024);
  passA1_kernel<<<ewBlocks, 256, 0, stream>>>(h0, ssrc, sdst, u1, c1, qs, E);
  passB_kernel<true, false><<<N, 256, 0, stream>>>(rowptr, ssrc, qs, y, c1, b1,
                                                   nullptr, h0, (float*)d_out, nullptr);

  // ---- Output 1: edge_index ----
  edgecopy_kernel<<<(2 * E + 255) / 256, 256, 0, stream>>>(
      ei, (float*)d_out + (size_t)N * 256, 2 * E);
}

// Round 4
// 566.478 us; speedup vs baseline: 4.4652x; 1.2552x over previous
//
#include <hip/hip_runtime.h>
#include <hip/hip_bf16.h>

typedef __hip_bfloat16 bf16;

typedef short bf16x8 __attribute__((ext_vector_type(8)));   // 8 bf16 (4 VGPRs), MFMA A/B frag
typedef float f32x4  __attribute__((ext_vector_type(4)));   // MFMA C/D frag

__device__ __forceinline__ float bflo(unsigned v){ union{unsigned u; float f;} c; c.u = v << 16; return c.f; }
__device__ __forceinline__ float bfhi(unsigned v){ union{unsigned u; float f;} c; c.u = v & 0xffff0000u; return c.f; }

// ---------------------------------------------------------------------------
// Weight transpose: B[K][NC] -> Bt[NC][K]. LDS 32x33 tile. K,NC multiples of 32.
// ---------------------------------------------------------------------------
__global__ __launch_bounds__(256) void transpose_kernel(
    const bf16* __restrict__ B, bf16* __restrict__ Bt, int K, int NC)
{
  __shared__ bf16 t[32][33];
  const int bx = blockIdx.x;            // along NC
  const int by = blockIdx.y;            // along K
  const int tx = threadIdx.x & 31, ty = threadIdx.x >> 5;  // ty 0..7
  #pragma unroll
  for (int i = 0; i < 32; i += 8)
    t[ty + i][tx] = B[(size_t)(by * 32 + ty + i) * NC + bx * 32 + tx];
  __syncthreads();
  #pragma unroll
  for (int i = 0; i < 32; i += 8)
    Bt[(size_t)(bx * 32 + ty + i) * K + by * 32 + tx] = t[tx][ty + i];
}

// ---------------------------------------------------------------------------
// MFMA GEMM: C[M x NC] = A[M x K](bf16, row-major) @ Bt[NC x K](bf16, n-major)
// 128x128 block tile, 4 waves (2x2), each wave 4x4 of 16x16x32 MFMA, BK=32.
// Column blocks with col0 < nsplit  -> bf16 store to Cy (ld=ldy), no bias.
// Column blocks with col0 >= nsplit -> f32 store to Cs (ld=lds_) + bias.
// ---------------------------------------------------------------------------
__global__ __launch_bounds__(256) void gemm_mfma_kernel(
    const bf16* __restrict__ A, const bf16* __restrict__ Bt,
    int M, int K,
    bf16* __restrict__ Cy, int ldy, int nsplit,
    float* __restrict__ Cs, const bf16* __restrict__ sbias, int lds_)
{
  constexpr int LDA = 40;                       // padded LDS row stride (bf16 elems), 80B
  __shared__ __align__(16) bf16 As[128 * LDA];  // 10240 B
  __shared__ __align__(16) bf16 Bs[128 * LDA];  // 10240 B

  const int tid  = threadIdx.x;
  const int row0 = blockIdx.x * 128;
  const int col0 = blockIdx.y * 128;
  const int lane = tid & 63;
  const int wave = tid >> 6;
  const int wm   = wave & 1, wn = wave >> 1;
  const int ln   = lane & 15, quad = lane >> 4;

  f32x4 acc[4][4] = {};

  for (int k0 = 0; k0 < K; k0 += 32) {
    // stage A and Bt tiles: 128 rows x 32 k each = 512 chunks of 16B; 2 per thread
    #pragma unroll
    for (int rep = 0; rep < 2; ++rep) {
      const int cs = tid + rep * 256;
      const int r  = cs >> 2;
      const int kp = (cs & 3) << 3;
      const int gr = min(row0 + r, M - 1);      // clamp: dup rows only feed unstored C rows
      const uint4 va = *(const uint4*)(A  + (size_t)gr * K        + k0 + kp);
      *(uint4*)(As + r * LDA + kp) = va;
      const uint4 vb = *(const uint4*)(Bt + (size_t)(col0 + r) * K + k0 + kp);
      *(uint4*)(Bs + r * LDA + kp) = vb;
    }
    __syncthreads();

    bf16x8 a[4], b[4];
    #pragma unroll
    for (int mi = 0; mi < 4; ++mi)
      a[mi] = *(const bf16x8*)(As + (wm * 64 + mi * 16 + ln) * LDA + quad * 8);
    #pragma unroll
    for (int ni = 0; ni < 4; ++ni)
      b[ni] = *(const bf16x8*)(Bs + (wn * 64 + ni * 16 + ln) * LDA + quad * 8);
    #pragma unroll
    for (int mi = 0; mi < 4; ++mi)
      #pragma unroll
      for (int ni = 0; ni < 4; ++ni)
        acc[mi][ni] = __builtin_amdgcn_mfma_f32_16x16x32_bf16(a[mi], b[ni], acc[mi][ni], 0, 0, 0);
    __syncthreads();
  }

  // epilogue: C[row=quad*4+r][col=ln] per 16x16 tile
  if (col0 < nsplit) {
    #pragma unroll
    for (int mi = 0; mi < 4; ++mi) {
      const int rbase = row0 + wm * 64 + mi * 16 + quad * 4;
      #pragma unroll
      for (int ni = 0; ni < 4; ++ni) {
        const int col = col0 + wn * 64 + ni * 16 + ln;
        #pragma unroll
        for (int r = 0; r < 4; ++r) {
          const int gr = rbase + r;
          if (gr < M) Cy[(size_t)gr * ldy + col] = __float2bfloat16(acc[mi][ni][r]);
        }
      }
    }
  } else {
    const int cbase = col0 - nsplit;
    #pragma unroll
    for (int mi = 0; mi < 4; ++mi) {
      const int rbase = row0 + wm * 64 + mi * 16 + quad * 4;
      #pragma unroll
      for (int ni = 0; ni < 4; ++ni) {
        const int col = cbase + wn * 64 + ni * 16 + ln;
        const float bb = __bfloat162float(sbias[col]);
        #pragma unroll
        for (int r = 0; r < 4; ++r) {
          const int gr = rbase + r;
          if (gr < M) Cs[(size_t)gr * lds_ + col] = acc[mi][ni][r] + bb;
        }
      }
    }
  }
}

// ---------------------------------------------------------------------------
// Edge sorting by dst: histogram -> single-block scan -> scatter
// ---------------------------------------------------------------------------
__global__ __launch_bounds__(256) void hist_kernel(
    const int* __restrict__ ei, int* __restrict__ deg, int E)
{
  const int e = (int)((unsigned)blockIdx.x * 256u + threadIdx.x);
  if (e < E) atomicAdd(deg + ei[E + e], 1);
}

__global__ __launch_bounds__(256) void scan_kernel(
    const int* __restrict__ deg, int* __restrict__ rowptr, int N)
{
  __shared__ int part[256];
  const int t = threadIdx.x;
  const int chunk = (N + 255) / 256;
  const int start = t * chunk;
  const int stop  = min(start + chunk, N);
  int sum = 0;
  for (int j = start; j < stop; ++j) sum += deg[j];
  part[t] = sum;
  __syncthreads();
  for (int off = 1; off < 256; off <<= 1) {
    int v = (t >= off) ? part[t - off] : 0;
    __syncthreads();
    part[t] += v;
    __syncthreads();
  }
  int base = (t == 0) ? 0 : part[t - 1];
  for (int j = start; j < stop; ++j) { rowptr[j] = base; base += deg[j]; }
  if (t == 255) rowptr[N] = part[255];
}

__global__ __launch_bounds__(256) void scatter_kernel(
    const int* __restrict__ ei, const int* __restrict__ rowptr,
    int* __restrict__ cursor, int* __restrict__ ssrc, int* __restrict__ sdst, int E)
{
  const int e = (int)((unsigned)blockIdx.x * 256u + threadIdx.x);
  if (e >= E) return;
  const int src = ei[e];
  const int d   = ei[E + e];
  const int p   = rowptr[d] + atomicAdd(cursor + d, 1);
  ssrc[p] = src;
  sdst[p] = d;
}

// ---------------------------------------------------------------------------
// Pass A: per sorted edge, softmax attention q[e][4]. One wave/edge.
// ---------------------------------------------------------------------------
__global__ __launch_bounds__(256) void passA0_kernel(
    const bf16* __restrict__ x, const int* __restrict__ ssrc,
    const int* __restrict__ sdst,
    const bf16* __restrict__ u, const bf16* __restrict__ cvec,
    float4* __restrict__ qs, int E)
{
  const int e = (int)(((unsigned)blockIdx.x * 256u + threadIdx.x) >> 6);
  if (e >= E) return;
  const int lane = threadIdx.x & 63;
  const int src = ssrc[e];
  const int dst = sdst[e];

  const unsigned xs = ((const unsigned*)(x + (size_t)src * 128))[lane];
  const unsigned xd = ((const unsigned*)(x + (size_t)dst * 128))[lane];
  const float d0 = bflo(xs) - bflo(xd);
  const float d1 = bfhi(xs) - bfhi(xd);

  const uint4 uv = *(const uint4*)(u + (size_t)lane * 8);
  float t0 = d0 * bflo(uv.x) + d1 * bflo(uv.z);
  float t1 = d0 * bfhi(uv.x) + d1 * bfhi(uv.z);
  float t2 = d0 * bflo(uv.y) + d1 * bflo(uv.w);
  float t3 = d0 * bfhi(uv.y) + d1 * bfhi(uv.w);
  #pragma unroll
  for (int off = 32; off > 0; off >>= 1) {
    t0 += __shfl_xor(t0, off);
    t1 += __shfl_xor(t1, off);
    t2 += __shfl_xor(t2, off);
    t3 += __shfl_xor(t3, off);
  }
  if (lane == 0) {
    t0 += __bfloat162float(cvec[0]);
    t1 += __bfloat162float(cvec[1]);
    t2 += __bfloat162float(cvec[2]);
    t3 += __bfloat162float(cvec[3]);
    const float mx = fmaxf(fmaxf(t0, t1), fmaxf(t2, t3));
    const float e0 = __expf(t0 - mx), e1 = __expf(t1 - mx);
    const float e2 = __expf(t2 - mx), e3 = __expf(t3 - mx);
    const float inv = 1.f / (e0 + e1 + e2 + e3);
    qs[e] = make_float4(e0 * inv, e1 * inv, e2 * inv, e3 * inv);
  }
}

__global__ __launch_bounds__(256) void passA1_kernel(
    const bf16* __restrict__ h0, const int* __restrict__ ssrc,
    const int* __restrict__ sdst,
    const bf16* __restrict__ u, const bf16* __restrict__ cvec,
    float4* __restrict__ qs, int E)
{
  const int e = (int)(((unsigned)blockIdx.x * 256u + threadIdx.x) >> 6);
  if (e >= E) return;
  const int lane = threadIdx.x & 63;
  const int src = ssrc[e];
  const int dst = sdst[e];

  const uint2 hs = *(const uint2*)(h0 + (size_t)src * 256 + lane * 4);
  const uint2 hd = *(const uint2*)(h0 + (size_t)dst * 256 + lane * 4);
  const float d0 = bflo(hs.x) - bflo(hd.x);
  const float d1 = bfhi(hs.x) - bfhi(hd.x);
  const float d2 = bflo(hs.y) - bflo(hd.y);
  const float d3 = bfhi(hs.y) - bfhi(hd.y);

  const uint4 ua = *(const uint4*)(u + (size_t)lane * 16);
  const uint4 ub = *(const uint4*)(u + (size_t)lane * 16 + 8);
  float t0 = d0*bflo(ua.x) + d1*bflo(ua.z) + d2*bflo(ub.x) + d3*bflo(ub.z);
  float t1 = d0*bfhi(ua.x) + d1*bfhi(ua.z) + d2*bfhi(ub.x) + d3*bfhi(ub.z);
  float t2 = d0*bflo(ua.y) + d1*bflo(ua.w) + d2*bflo(ub.y) + d3*bflo(ub.w);
  float t3 = d0*bfhi(ua.y) + d1*bfhi(ua.w) + d2*bfhi(ub.y) + d3*bfhi(ub.w);
  #pragma unroll
  for (int off = 32; off > 0; off >>= 1) {
    t0 += __shfl_xor(t0, off);
    t1 += __shfl_xor(t1, off);
    t2 += __shfl_xor(t2, off);
    t3 += __shfl_xor(t3, off);
  }
  if (lane == 0) {
    t0 += __bfloat162float(cvec[0]);
    t1 += __bfloat162float(cvec[1]);
    t2 += __bfloat162float(cvec[2]);
    t3 += __bfloat162float(cvec[3]);
    const float mx = fmaxf(fmaxf(t0, t1), fmaxf(t2, t3));
    const float e0 = __expf(t0 - mx), e1 = __expf(t1 - mx);
    const float e2 = __expf(t2 - mx), e3 = __expf(t3 - mx);
    const float inv = 1.f / (e0 + e1 + e2 + e3);
    qs[e] = make_float4(e0 * inv, e1 * inv, e2 * inv, e3 * inv);
  }
}

// ---------------------------------------------------------------------------
// Pass B: one block per dst node, thread = output channel. No atomics.
// ---------------------------------------------------------------------------
template<bool OUT_FLOAT, bool SKIP_FLOAT>
__global__ __launch_bounds__(256) void passB_kernel(
    const int* __restrict__ rowptr, const int* __restrict__ ssrc,
    const float4* __restrict__ qs, const bf16* __restrict__ y,
    const bf16* __restrict__ cvec, const bf16* __restrict__ bias,
    const float* __restrict__ skipf, const bf16* __restrict__ skipb,
    float* __restrict__ outf, bf16* __restrict__ outb)
{
  const int i = blockIdx.x;
  const int k = threadIdx.x;
  const int beg = rowptr[i], end = rowptr[i + 1];

  float acc = 0.f;
  for (int e = beg; e < end; ++e) {
    const int src = ssrc[e];
    const float4 q = qs[e];
    const bf16* yb = y + (size_t)src * 1024 + k;
    acc += q.x * __bfloat162float(yb[0])
         + q.y * __bfloat162float(yb[256])
         + q.z * __bfloat162float(yb[512])
         + q.w * __bfloat162float(yb[768]);
  }

  const float c0 = __bfloat162float(cvec[0]), c1 = __bfloat162float(cvec[1]);
  const float c2 = __bfloat162float(cvec[2]), c3 = __bfloat162float(cvec[3]);
  const float mx = fmaxf(fmaxf(c0, c1), fmaxf(c2, c3));
  const float e0 = __expf(c0 - mx), e1 = __expf(c1 - mx);
  const float e2 = __expf(c2 - mx), e3 = __expf(c3 - mx);
  const float inv = 1.f / (e0 + e1 + e2 + e3);
  const bf16* yi = y + (size_t)i * 1024 + k;
  acc += (e0 * __bfloat162float(yi[0])   + e1 * __bfloat162float(yi[256])
        + e2 * __bfloat162float(yi[512]) + e3 * __bfloat162float(yi[768])) * inv;

  const int idx = i * 256 + k;
  float v = acc / (float)(end - beg + 1) + __bfloat162float(bias[k]);
  v += SKIP_FLOAT ? skipf[idx] : __bfloat162float(skipb[idx]);
  v = fmaxf(v, 0.f);
  if (OUT_FLOAT) outf[idx] = v;
  else           outb[idx] = __float2bfloat16(v);
}

// Output 1: edge_index values written as float32
__global__ __launch_bounds__(256) void edgecopy_kernel(
    const int* __restrict__ ei, float* __restrict__ out, int n)
{
  const int i = (int)((unsigned)blockIdx.x * 256u + threadIdx.x);
  if (i < n) out[i] = (float)ei[i];
}

extern "C" void kernel_launch(void* const* d_in, const int* in_sizes, int n_in,
                              void* d_out, int out_size, void* d_ws, size_t ws_size,
                              hipStream_t stream)
{
  const bf16* x   = (const bf16*)d_in[0];
  const int*  ei  = (const int*)d_in[1];
  const bf16* W0  = (const bf16*)d_in[2];
  const bf16* u0  = (const bf16*)d_in[3];
  const bf16* c0  = (const bf16*)d_in[4];
  const bf16* b0  = (const bf16*)d_in[5];
  const bf16* sW0 = (const bf16*)d_in[6];
  const bf16* sb0 = (const bf16*)d_in[7];
  const bf16* W1  = (const bf16*)d_in[8];
  const bf16* u1  = (const bf16*)d_in[9];
  const bf16* c1  = (const bf16*)d_in[10];
  const bf16* b1  = (const bf16*)d_in[11];

  const int N = in_sizes[0] / 128;   // 20000
  const int E = in_sizes[1] / 2;     // 320000

  // workspace layout (~83 MB)
  char* ws = (char*)d_ws;
  bf16*   y      = (bf16*)ws;   ws += (size_t)N * 1024 * sizeof(bf16);
  float*  skip0  = (float*)ws;  ws += (size_t)N * 256 * sizeof(float);
  bf16*   h0     = (bf16*)ws;   ws += (size_t)N * 256 * sizeof(bf16);
  float4* qs     = (float4*)ws; ws += (size_t)E * sizeof(float4);
  int*    ssrc   = (int*)ws;    ws += (size_t)E * sizeof(int);
  int*    sdst   = (int*)ws;    ws += (size_t)E * sizeof(int);
  int*    deg    = (int*)ws;    ws += (size_t)N * sizeof(int);
  int*    cursor = (int*)ws;    ws += (size_t)N * sizeof(int);
  int*    rowptr = (int*)ws;    ws += ((size_t)N + 1) * sizeof(int);
  bf16*   Bt0    = (bf16*)ws;   ws += (size_t)1280 * 128 * sizeof(bf16);  // [W0|sW0]^T
  bf16*   Bt1    = (bf16*)ws;   ws += (size_t)1024 * 256 * sizeof(bf16);  // W1^T

  hipMemsetAsync(deg, 0, 2 * (size_t)N * sizeof(int), stream);  // deg + cursor

  const int eBlocks  = (E + 255) / 256;
  const int ewBlocks = (E * 64 + 255) / 256;
  const int mTiles   = (N + 127) / 128;

  // ---- weight transposes (cheap; inputs re-poisoned each call) ----
  transpose_kernel<<<dim3(1024/32, 128/32), 256, 0, stream>>>(W0,  Bt0,               128, 1024);
  transpose_kernel<<<dim3( 256/32, 128/32), 256, 0, stream>>>(sW0, Bt0 + 1024 * 128,  128,  256);
  transpose_kernel<<<dim3(1024/32, 256/32), 256, 0, stream>>>(W1,  Bt1,               256, 1024);

  // ---- sort edges by dst ----
  hist_kernel<<<eBlocks, 256, 0, stream>>>(ei, deg, E);
  scan_kernel<<<1, 256, 0, stream>>>(deg, rowptr, N);
  scatter_kernel<<<eBlocks, 256, 0, stream>>>(ei, rowptr, cursor, ssrc, sdst, E);

  // ---- Block 0: fused y0 (cols 0..1023 -> y) + skip (cols 1024..1279 -> skip0) ----
  gemm_mfma_kernel<<<dim3(mTiles, 10), 256, 0, stream>>>(
      x, Bt0, N, 128, y, 1024, 1024, skip0, sb0, 256);
  passA0_kernel<<<ewBlocks, 256, 0, stream>>>(x, ssrc, sdst, u0, c0, qs, E);
  passB_kernel<false, true><<<N, 256, 0, stream>>>(rowptr, ssrc, qs, y, c0, b0,
                                                   skip0, nullptr, nullptr, h0);

  // ---- Block 1 ----
  gemm_mfma_kernel<<<dim3(mTiles, 8), 256, 0, stream>>>(
      h0, Bt1, N, 256, y, 1024, 1024, nullptr, nullptr, 256);
  passA1_kernel<<<ewBlocks, 256, 0, stream>>>(h0, ssrc, sdst, u1, c1, qs, E);
  passB_kernel<true, false><<<N, 256, 0, stream>>>(rowptr, ssrc, qs, y, c1, b1,
                                                   nullptr, h0, (float*)d_out, nullptr);

  // ---- Output 1: edge_index ----
  edgecopy_kernel<<<(2 * E + 255) / 256, 256, 0, stream>>>(
      ei, (float*)d_out + (size_t)N * 256, 2 * E);
}

// Round 5
// 476.246 us; speedup vs baseline: 5.3112x; 1.1895x over previous
//
#include <hip/hip_runtime.h>
#include <hip/hip_bf16.h>

typedef __hip_bfloat16 bf16;

typedef short bf16x8 __attribute__((ext_vector_type(8)));   // 8 bf16 (4 VGPRs), MFMA A/B frag
typedef float f32x4  __attribute__((ext_vector_type(4)));   // MFMA C/D frag

__device__ __forceinline__ float bflo(unsigned v){ union{unsigned u; float f;} c; c.u = v << 16; return c.f; }
__device__ __forceinline__ float bfhi(unsigned v){ union{unsigned u; float f;} c; c.u = v & 0xffff0000u; return c.f; }

// ---------------------------------------------------------------------------
// Weight transpose: B[K][NC] -> Bt[NC][K]. LDS 32x33 tile. K,NC multiples of 32.
// ---------------------------------------------------------------------------
__global__ __launch_bounds__(256) void transpose_kernel(
    const bf16* __restrict__ B, bf16* __restrict__ Bt, int K, int NC)
{
  __shared__ bf16 t[32][33];
  const int bx = blockIdx.x;            // along NC
  const int by = blockIdx.y;            // along K
  const int tx = threadIdx.x & 31, ty = threadIdx.x >> 5;  // ty 0..7
  #pragma unroll
  for (int i = 0; i < 32; i += 8)
    t[ty + i][tx] = B[(size_t)(by * 32 + ty + i) * NC + bx * 32 + tx];
  __syncthreads();
  #pragma unroll
  for (int i = 0; i < 32; i += 8)
    Bt[(size_t)(bx * 32 + ty + i) * K + by * 32 + tx] = t[tx][ty + i];
}

// ---------------------------------------------------------------------------
// MFMA GEMM: C[M x NC] = A[M x K](bf16, row-major) @ Bt[NC x K](bf16, n-major)
// 128x128 block tile, 4 waves (2x2), each wave 4x4 of 16x16x32 MFMA, BK=32.
// col0 <  nsplit -> bf16 store to Cy in HEAD-INTERLEAVED layout:
//                   Cy[row][ (col&255)*4 + (col>>8) ]  (y[node][channel][head])
// col0 >= nsplit -> f32 store to Cs (ld=lds_) + bias (normal layout).
// ---------------------------------------------------------------------------
__global__ __launch_bounds__(256) void gemm_mfma_kernel(
    const bf16* __restrict__ A, const bf16* __restrict__ Bt,
    int M, int K,
    bf16* __restrict__ Cy, int ldy, int nsplit,
    float* __restrict__ Cs, const bf16* __restrict__ sbias, int lds_)
{
  constexpr int LDA = 40;                       // padded LDS row stride (bf16 elems), 80B
  __shared__ __align__(16) bf16 As[128 * LDA];  // 10240 B
  __shared__ __align__(16) bf16 Bs[128 * LDA];  // 10240 B

  const int tid  = threadIdx.x;
  const int row0 = blockIdx.x * 128;
  const int col0 = blockIdx.y * 128;
  const int lane = tid & 63;
  const int wave = tid >> 6;
  const int wm   = wave & 1, wn = wave >> 1;
  const int ln   = lane & 15, quad = lane >> 4;

  f32x4 acc[4][4] = {};

  for (int k0 = 0; k0 < K; k0 += 32) {
    #pragma unroll
    for (int rep = 0; rep < 2; ++rep) {
      const int cs = tid + rep * 256;
      const int r  = cs >> 2;
      const int kp = (cs & 3) << 3;
      const int gr = min(row0 + r, M - 1);      // clamp: dup rows only feed unstored C rows
      const uint4 va = *(const uint4*)(A  + (size_t)gr * K        + k0 + kp);
      *(uint4*)(As + r * LDA + kp) = va;
      const uint4 vb = *(const uint4*)(Bt + (size_t)(col0 + r) * K + k0 + kp);
      *(uint4*)(Bs + r * LDA + kp) = vb;
    }
    __syncthreads();

    bf16x8 a[4], b[4];
    #pragma unroll
    for (int mi = 0; mi < 4; ++mi)
      a[mi] = *(const bf16x8*)(As + (wm * 64 + mi * 16 + ln) * LDA + quad * 8);
    #pragma unroll
    for (int ni = 0; ni < 4; ++ni)
      b[ni] = *(const bf16x8*)(Bs + (wn * 64 + ni * 16 + ln) * LDA + quad * 8);
    #pragma unroll
    for (int mi = 0; mi < 4; ++mi)
      #pragma unroll
      for (int ni = 0; ni < 4; ++ni)
        acc[mi][ni] = __builtin_amdgcn_mfma_f32_16x16x32_bf16(a[mi], b[ni], acc[mi][ni], 0, 0, 0);
    __syncthreads();
  }

  // epilogue: C[row=quad*4+r][col=ln] per 16x16 tile
  if (col0 < nsplit) {
    #pragma unroll
    for (int mi = 0; mi < 4; ++mi) {
      const int rbase = row0 + wm * 64 + mi * 16 + quad * 4;
      #pragma unroll
      for (int ni = 0; ni < 4; ++ni) {
        const int col = col0 + wn * 64 + ni * 16 + ln;
        const int ic  = (col & 255) * 4 + (col >> 8);   // head-interleaved position
        #pragma unroll
        for (int r = 0; r < 4; ++r) {
          const int gr = rbase + r;
          if (gr < M) Cy[(size_t)gr * ldy + ic] = __float2bfloat16(acc[mi][ni][r]);
        }
      }
    }
  } else {
    const int cbase = col0 - nsplit;
    #pragma unroll
    for (int mi = 0; mi < 4; ++mi) {
      const int rbase = row0 + wm * 64 + mi * 16 + quad * 4;
      #pragma unroll
      for (int ni = 0; ni < 4; ++ni) {
        const int col = cbase + wn * 64 + ni * 16 + ln;
        const float bb = __bfloat162float(sbias[col]);
        #pragma unroll
        for (int r = 0; r < 4; ++r) {
          const int gr = rbase + r;
          if (gr < M) Cs[(size_t)gr * lds_ + col] = acc[mi][ni][r] + bb;
        }
      }
    }
  }
}

// ---------------------------------------------------------------------------
// Edge sorting by dst: histogram -> single-block scan -> scatter
// ---------------------------------------------------------------------------
__global__ __launch_bounds__(256) void hist_kernel(
    const int* __restrict__ ei, int* __restrict__ deg, int E)
{
  const int e = (int)((unsigned)blockIdx.x * 256u + threadIdx.x);
  if (e < E) atomicAdd(deg + ei[E + e], 1);
}

__global__ __launch_bounds__(256) void scan_kernel(
    const int* __restrict__ deg, int* __restrict__ rowptr, int N)
{
  __shared__ int part[256];
  const int t = threadIdx.x;
  const int chunk = (N + 255) / 256;
  const int start = t * chunk;
  const int stop  = min(start + chunk, N);
  int sum = 0;
  for (int j = start; j < stop; ++j) sum += deg[j];
  part[t] = sum;
  __syncthreads();
  for (int off = 1; off < 256; off <<= 1) {
    int v = (t >= off) ? part[t - off] : 0;
    __syncthreads();
    part[t] += v;
    __syncthreads();
  }
  int base = (t == 0) ? 0 : part[t - 1];
  for (int j = start; j < stop; ++j) { rowptr[j] = base; base += deg[j]; }
  if (t == 255) rowptr[N] = part[255];
}

__global__ __launch_bounds__(256) void scatter_kernel(
    const int* __restrict__ ei, const int* __restrict__ rowptr,
    int* __restrict__ cursor, int* __restrict__ ssrc, int* __restrict__ sdst, int E)
{
  const int e = (int)((unsigned)blockIdx.x * 256u + threadIdx.x);
  if (e >= E) return;
  const int src = ei[e];
  const int d   = ei[E + e];
  const int p   = rowptr[d] + atomicAdd(cursor + d, 1);
  ssrc[p] = src;
  sdst[p] = d;
}

// ---------------------------------------------------------------------------
// Projection: p[i][h] = sum_k feat[i][k] * u[k][h].  One wave per node.
// C=128: lane owns 2 channels; C=256: lane owns 4 channels.
// ---------------------------------------------------------------------------
__global__ __launch_bounds__(256) void proj128_kernel(
    const bf16* __restrict__ x, const bf16* __restrict__ u,
    float4* __restrict__ p, int N)
{
  const int node = (int)(((unsigned)blockIdx.x * 256u + threadIdx.x) >> 6);
  if (node >= N) return;
  const int lane = threadIdx.x & 63;
  const unsigned xv = ((const unsigned*)(x + (size_t)node * 128))[lane];
  const float d0 = bflo(xv), d1 = bfhi(xv);
  const uint4 uv = *(const uint4*)(u + (size_t)lane * 8);
  float t0 = d0 * bflo(uv.x) + d1 * bflo(uv.z);
  float t1 = d0 * bfhi(uv.x) + d1 * bfhi(uv.z);
  float t2 = d0 * bflo(uv.y) + d1 * bflo(uv.w);
  float t3 = d0 * bfhi(uv.y) + d1 * bfhi(uv.w);
  #pragma unroll
  for (int off = 32; off > 0; off >>= 1) {
    t0 += __shfl_xor(t0, off);
    t1 += __shfl_xor(t1, off);
    t2 += __shfl_xor(t2, off);
    t3 += __shfl_xor(t3, off);
  }
  if (lane == 0) p[node] = make_float4(t0, t1, t2, t3);
}

__global__ __launch_bounds__(256) void proj256_kernel(
    const bf16* __restrict__ h, const bf16* __restrict__ u,
    float4* __restrict__ p, int N)
{
  const int node = (int)(((unsigned)blockIdx.x * 256u + threadIdx.x) >> 6);
  if (node >= N) return;
  const int lane = threadIdx.x & 63;
  const uint2 hv = *(const uint2*)(h + (size_t)node * 256 + lane * 4);
  const float d0 = bflo(hv.x), d1 = bfhi(hv.x);
  const float d2 = bflo(hv.y), d3 = bfhi(hv.y);
  const uint4 ua = *(const uint4*)(u + (size_t)lane * 16);
  const uint4 ub = *(const uint4*)(u + (size_t)lane * 16 + 8);
  float t0 = d0*bflo(ua.x) + d1*bflo(ua.z) + d2*bflo(ub.x) + d3*bflo(ub.z);
  float t1 = d0*bfhi(ua.x) + d1*bfhi(ua.z) + d2*bfhi(ub.x) + d3*bfhi(ub.z);
  float t2 = d0*bflo(ua.y) + d1*bflo(ua.w) + d2*bflo(ub.y) + d3*bflo(ub.w);
  float t3 = d0*bfhi(ua.y) + d1*bfhi(ua.w) + d2*bfhi(ub.y) + d3*bfhi(ub.w);
  #pragma unroll
  for (int off = 32; off > 0; off >>= 1) {
    t0 += __shfl_xor(t0, off);
    t1 += __shfl_xor(t1, off);
    t2 += __shfl_xor(t2, off);
    t3 += __shfl_xor(t3, off);
  }
  if (lane == 0) p[node] = make_float4(t0, t1, t2, t3);
}

// ---------------------------------------------------------------------------
// Pass A: per sorted edge, q = softmax(p[src] - p[dst] + c). Thread per edge.
// ---------------------------------------------------------------------------
__global__ __launch_bounds__(256) void passA_kernel(
    const float4* __restrict__ p, const int* __restrict__ ssrc,
    const int* __restrict__ sdst, const bf16* __restrict__ cvec,
    float4* __restrict__ qs, int E)
{
  const int e = (int)((unsigned)blockIdx.x * 256u + threadIdx.x);
  if (e >= E) return;
  const float4 ps = p[ssrc[e]];
  const float4 pd = p[sdst[e]];
  const float t0 = ps.x - pd.x + __bfloat162float(cvec[0]);
  const float t1 = ps.y - pd.y + __bfloat162float(cvec[1]);
  const float t2 = ps.z - pd.z + __bfloat162float(cvec[2]);
  const float t3 = ps.w - pd.w + __bfloat162float(cvec[3]);
  const float mx = fmaxf(fmaxf(t0, t1), fmaxf(t2, t3));
  const float e0 = __expf(t0 - mx), e1 = __expf(t1 - mx);
  const float e2 = __expf(t2 - mx), e3 = __expf(t3 - mx);
  const float inv = 1.f / (e0 + e1 + e2 + e3);
  qs[e] = make_float4(e0 * inv, e1 * inv, e2 * inv, e3 * inv);
}

// ---------------------------------------------------------------------------
// Pass B: one block per dst node, thread = output channel. y is
// head-interleaved [node][channel][head] -> one uint2 (4 bf16) per edge.
// ---------------------------------------------------------------------------
template<bool OUT_FLOAT, bool SKIP_FLOAT>
__global__ __launch_bounds__(256) void passB_kernel(
    const int* __restrict__ rowptr, const int* __restrict__ ssrc,
    const float4* __restrict__ qs, const bf16* __restrict__ y,
    const bf16* __restrict__ cvec, const bf16* __restrict__ bias,
    const float* __restrict__ skipf, const bf16* __restrict__ skipb,
    float* __restrict__ outf, bf16* __restrict__ outb)
{
  const int i = blockIdx.x;
  const int k = threadIdx.x;
  const int beg = rowptr[i], end = rowptr[i + 1];

  float acc = 0.f;
  for (int e = beg; e < end; ++e) {
    const int src = ssrc[e];
    const float4 q = qs[e];
    const uint2 v = *(const uint2*)(y + (size_t)src * 1024 + k * 4);
    acc += q.x * bflo(v.x) + q.y * bfhi(v.x)
         + q.z * bflo(v.y) + q.w * bfhi(v.y);
  }

  const float c0 = __bfloat162float(cvec[0]), c1 = __bfloat162float(cvec[1]);
  const float c2 = __bfloat162float(cvec[2]), c3 = __bfloat162float(cvec[3]);
  const float mx = fmaxf(fmaxf(c0, c1), fmaxf(c2, c3));
  const float e0 = __expf(c0 - mx), e1 = __expf(c1 - mx);
  const float e2 = __expf(c2 - mx), e3 = __expf(c3 - mx);
  const float inv = 1.f / (e0 + e1 + e2 + e3);
  const uint2 vi = *(const uint2*)(y + (size_t)i * 1024 + k * 4);
  acc += (e0 * bflo(vi.x) + e1 * bfhi(vi.x)
        + e2 * bflo(vi.y) + e3 * bfhi(vi.y)) * inv;

  const int idx = i * 256 + k;
  float v = acc / (float)(end - beg + 1) + __bfloat162float(bias[k]);
  v += SKIP_FLOAT ? skipf[idx] : __bfloat162float(skipb[idx]);
  v = fmaxf(v, 0.f);
  if (OUT_FLOAT) outf[idx] = v;
  else           outb[idx] = __float2bfloat16(v);
}

// Output 1: edge_index values written as float32
__global__ __launch_bounds__(256) void edgecopy_kernel(
    const int* __restrict__ ei, float* __restrict__ out, int n)
{
  const int i = (int)((unsigned)blockIdx.x * 256u + threadIdx.x);
  if (i < n) out[i] = (float)ei[i];
}

extern "C" void kernel_launch(void* const* d_in, const int* in_sizes, int n_in,
                              void* d_out, int out_size, void* d_ws, size_t ws_size,
                              hipStream_t stream)
{
  const bf16* x   = (const bf16*)d_in[0];
  const int*  ei  = (const int*)d_in[1];
  const bf16* W0  = (const bf16*)d_in[2];
  const bf16* u0  = (const bf16*)d_in[3];
  const bf16* c0  = (const bf16*)d_in[4];
  const bf16* b0  = (const bf16*)d_in[5];
  const bf16* sW0 = (const bf16*)d_in[6];
  const bf16* sb0 = (const bf16*)d_in[7];
  const bf16* W1  = (const bf16*)d_in[8];
  const bf16* u1  = (const bf16*)d_in[9];
  const bf16* c1  = (const bf16*)d_in[10];
  const bf16* b1  = (const bf16*)d_in[11];

  const int N = in_sizes[0] / 128;   // 20000
  const int E = in_sizes[1] / 2;     // 320000

  // workspace layout (~84 MB)
  char* ws = (char*)d_ws;
  bf16*   y      = (bf16*)ws;   ws += (size_t)N * 1024 * sizeof(bf16);   // head-interleaved
  float*  skip0  = (float*)ws;  ws += (size_t)N * 256 * sizeof(float);
  bf16*   h0     = (bf16*)ws;   ws += (size_t)N * 256 * sizeof(bf16);
  float4* qs     = (float4*)ws; ws += (size_t)E * sizeof(float4);
  float4* p      = (float4*)ws; ws += (size_t)N * sizeof(float4);
  int*    ssrc   = (int*)ws;    ws += (size_t)E * sizeof(int);
  int*    sdst   = (int*)ws;    ws += (size_t)E * sizeof(int);
  int*    deg    = (int*)ws;    ws += (size_t)N * sizeof(int);
  int*    cursor = (int*)ws;    ws += (size_t)N * sizeof(int);
  int*    rowptr = (int*)ws;    ws += ((size_t)N + 1) * sizeof(int);
  bf16*   Bt0    = (bf16*)ws;   ws += (size_t)1280 * 128 * sizeof(bf16); // [W0|sW0]^T
  bf16*   Bt1    = (bf16*)ws;   ws += (size_t)1024 * 256 * sizeof(bf16); // W1^T

  hipMemsetAsync(deg, 0, 2 * (size_t)N * sizeof(int), stream);  // deg + cursor

  const int eBlocks = (E + 255) / 256;
  const int nwBlocks = (N * 64 + 255) / 256;   // wave-per-node kernels
  const int mTiles  = (N + 127) / 128;

  // ---- weight transposes ----
  transpose_kernel<<<dim3(1024/32, 128/32), 256, 0, stream>>>(W0,  Bt0,               128, 1024);
  transpose_kernel<<<dim3( 256/32, 128/32), 256, 0, stream>>>(sW0, Bt0 + 1024 * 128,  128,  256);
  transpose_kernel<<<dim3(1024/32, 256/32), 256, 0, stream>>>(W1,  Bt1,               256, 1024);

  // ---- sort edges by dst ----
  hist_kernel<<<eBlocks, 256, 0, stream>>>(ei, deg, E);
  scan_kernel<<<1, 256, 0, stream>>>(deg, rowptr, N);
  scatter_kernel<<<eBlocks, 256, 0, stream>>>(ei, rowptr, cursor, ssrc, sdst, E);

  // ---- Block 0 ----
  proj128_kernel<<<nwBlocks, 256, 0, stream>>>(x, u0, p, N);
  gemm_mfma_kernel<<<dim3(mTiles, 10), 256, 0, stream>>>(
      x, Bt0, N, 128, y, 1024, 1024, skip0, sb0, 256);
  passA_kernel<<<eBlocks, 256, 0, stream>>>(p, ssrc, sdst, c0, qs, E);
  passB_kernel<false, true><<<N, 256, 0, stream>>>(rowptr, ssrc, qs, y, c0, b0,
                                                   skip0, nullptr, nullptr, h0);

  // ---- Block 1 ----
  proj256_kernel<<<nwBlocks, 256, 0, stream>>>(h0, u1, p, N);
  gemm_mfma_kernel<<<dim3(mTiles, 8), 256, 0, stream>>>(
      h0, Bt1, N, 256, y, 1024, 1024, nullptr, nullptr, 256);
  passA_kernel<<<eBlocks, 256, 0, stream>>>(p, ssrc, sdst, c1, qs, E);
  passB_kernel<true, false><<<N, 256, 0, stream>>>(rowptr, ssrc, qs, y, c1, b1,
                                                   nullptr, h0, (float*)d_out, nullptr);

  // ---- Output 1: edge_index ----
  edgecopy_kernel<<<(2 * E + 255) / 256, 256, 0, stream>>>(
      ei, (float*)d_out + (size_t)N * 256, 2 * E);
}

// Round 6
// 413.816 us; speedup vs baseline: 6.1124x; 1.1509x over previous
//
#include <hip/hip_runtime.h>
#include <hip/hip_bf16.h>

typedef __hip_bfloat16 bf16;

typedef short bf16x8 __attribute__((ext_vector_type(8)));   // 8 bf16 (4 VGPRs), MFMA A/B frag
typedef float f32x4  __attribute__((ext_vector_type(4)));   // MFMA C/D frag
typedef float f32x2  __attribute__((ext_vector_type(2)));

__device__ __forceinline__ float bflo(unsigned v){ union{unsigned u; float f;} c; c.u = v << 16; return c.f; }
__device__ __forceinline__ float bfhi(unsigned v){ union{unsigned u; float f;} c; c.u = v & 0xffff0000u; return c.f; }

// float -> fp8 e4m3 (OCP on gfx950), single byte
__device__ __forceinline__ unsigned char f32_to_fp8(float v){
  return (unsigned char)(__builtin_amdgcn_cvt_pk_fp8_f32(v, v, 0, false) & 0xFF);
}

// ---------------------------------------------------------------------------
// Weight transpose: B[K][NC] -> Bt[NC][K]. LDS 32x33 tile. K,NC multiples of 32.
// ---------------------------------------------------------------------------
__global__ __launch_bounds__(256) void transpose_kernel(
    const bf16* __restrict__ B, bf16* __restrict__ Bt, int K, int NC)
{
  __shared__ bf16 t[32][33];
  const int bx = blockIdx.x;            // along NC
  const int by = blockIdx.y;            // along K
  const int tx = threadIdx.x & 31, ty = threadIdx.x >> 5;  // ty 0..7
  #pragma unroll
  for (int i = 0; i < 32; i += 8)
    t[ty + i][tx] = B[(size_t)(by * 32 + ty + i) * NC + bx * 32 + tx];
  __syncthreads();
  #pragma unroll
  for (int i = 0; i < 32; i += 8)
    Bt[(size_t)(bx * 32 + ty + i) * K + by * 32 + tx] = t[tx][ty + i];
}

// ---------------------------------------------------------------------------
// MFMA GEMM: C[M x NC] = A[M x K](bf16, row-major) @ Bt[NC x K](bf16, n-major)
// 128x128 block tile, 4 waves (2x2), each wave 4x4 of 16x16x32 MFMA, BK=32.
// col0 <  nsplit -> fp8 byte store to Cy, HEAD-INTERLEAVED:
//                   Cy[row*1024 + (col&255)*4 + (col>>8)]   (y[node][ch][head])
// col0 >= nsplit -> f32 store to Cs (ld=lds_) + bias (normal layout).
// ---------------------------------------------------------------------------
__global__ __launch_bounds__(256) void gemm_mfma_kernel(
    const bf16* __restrict__ A, const bf16* __restrict__ Bt,
    int M, int K,
    unsigned char* __restrict__ Cy, int nsplit,
    float* __restrict__ Cs, const bf16* __restrict__ sbias, int lds_)
{
  constexpr int LDA = 40;                       // padded LDS row stride (bf16 elems), 80B
  __shared__ __align__(16) bf16 As[128 * LDA];  // 10240 B
  __shared__ __align__(16) bf16 Bs[128 * LDA];  // 10240 B

  const int tid  = threadIdx.x;
  const int row0 = blockIdx.x * 128;
  const int col0 = blockIdx.y * 128;
  const int lane = tid & 63;
  const int wave = tid >> 6;
  const int wm   = wave & 1, wn = wave >> 1;
  const int ln   = lane & 15, quad = lane >> 4;

  f32x4 acc[4][4] = {};

  for (int k0 = 0; k0 < K; k0 += 32) {
    #pragma unroll
    for (int rep = 0; rep < 2; ++rep) {
      const int cs = tid + rep * 256;
      const int r  = cs >> 2;
      const int kp = (cs & 3) << 3;
      const int gr = min(row0 + r, M - 1);      // clamp: dup rows only feed unstored C rows
      const uint4 va = *(const uint4*)(A  + (size_t)gr * K        + k0 + kp);
      *(uint4*)(As + r * LDA + kp) = va;
      const uint4 vb = *(const uint4*)(Bt + (size_t)(col0 + r) * K + k0 + kp);
      *(uint4*)(Bs + r * LDA + kp) = vb;
    }
    __syncthreads();

    bf16x8 a[4], b[4];
    #pragma unroll
    for (int mi = 0; mi < 4; ++mi)
      a[mi] = *(const bf16x8*)(As + (wm * 64 + mi * 16 + ln) * LDA + quad * 8);
    #pragma unroll
    for (int ni = 0; ni < 4; ++ni)
      b[ni] = *(const bf16x8*)(Bs + (wn * 64 + ni * 16 + ln) * LDA + quad * 8);
    #pragma unroll
    for (int mi = 0; mi < 4; ++mi)
      #pragma unroll
      for (int ni = 0; ni < 4; ++ni)
        acc[mi][ni] = __builtin_amdgcn_mfma_f32_16x16x32_bf16(a[mi], b[ni], acc[mi][ni], 0, 0, 0);
    __syncthreads();
  }

  // epilogue: C[row=quad*4+r][col=ln] per 16x16 tile
  if (col0 < nsplit) {
    #pragma unroll
    for (int mi = 0; mi < 4; ++mi) {
      const int rbase = row0 + wm * 64 + mi * 16 + quad * 4;
      #pragma unroll
      for (int ni = 0; ni < 4; ++ni) {
        const int col = col0 + wn * 64 + ni * 16 + ln;
        const int ic  = (col & 255) * 4 + (col >> 8);   // head-interleaved byte position
        #pragma unroll
        for (int r = 0; r < 4; ++r) {
          const int gr = rbase + r;
          if (gr < M) Cy[(size_t)gr * 1024 + ic] = f32_to_fp8(acc[mi][ni][r]);
        }
      }
    }
  } else {
    const int cbase = col0 - nsplit;
    #pragma unroll
    for (int mi = 0; mi < 4; ++mi) {
      const int rbase = row0 + wm * 64 + mi * 16 + quad * 4;
      #pragma unroll
      for (int ni = 0; ni < 4; ++ni) {
        const int col = cbase + wn * 64 + ni * 16 + ln;
        const float bb = __bfloat162float(sbias[col]);
        #pragma unroll
        for (int r = 0; r < 4; ++r) {
          const int gr = rbase + r;
          if (gr < M) Cs[(size_t)gr * lds_ + col] = acc[mi][ni][r] + bb;
        }
      }
    }
  }
}

// ---------------------------------------------------------------------------
// Edge sorting by dst: histogram -> single-block scan -> scatter
// ---------------------------------------------------------------------------
__global__ __launch_bounds__(256) void hist_kernel(
    const int* __restrict__ ei, int* __restrict__ deg, int E)
{
  const int e = (int)((unsigned)blockIdx.x * 256u + threadIdx.x);
  if (e < E) atomicAdd(deg + ei[E + e], 1);
}

__global__ __launch_bounds__(256) void scan_kernel(
    const int* __restrict__ deg, int* __restrict__ rowptr, int N)
{
  __shared__ int part[256];
  const int t = threadIdx.x;
  const int chunk = (N + 255) / 256;
  const int start = t * chunk;
  const int stop  = min(start + chunk, N);
  int sum = 0;
  for (int j = start; j < stop; ++j) sum += deg[j];
  part[t] = sum;
  __syncthreads();
  for (int off = 1; off < 256; off <<= 1) {
    int v = (t >= off) ? part[t - off] : 0;
    __syncthreads();
    part[t] += v;
    __syncthreads();
  }
  int base = (t == 0) ? 0 : part[t - 1];
  for (int j = start; j < stop; ++j) { rowptr[j] = base; base += deg[j]; }
  if (t == 255) rowptr[N] = part[255];
}

__global__ __launch_bounds__(256) void scatter_kernel(
    const int* __restrict__ ei, const int* __restrict__ rowptr,
    int* __restrict__ cursor, int* __restrict__ ssrc, int* __restrict__ sdst, int E)
{
  const int e = (int)((unsigned)blockIdx.x * 256u + threadIdx.x);
  if (e >= E) return;
  const int src = ei[e];
  const int d   = ei[E + e];
  const int p   = rowptr[d] + atomicAdd(cursor + d, 1);
  ssrc[p] = src;
  sdst[p] = d;
}

// ---------------------------------------------------------------------------
// Projection: p[i][h] = sum_k feat[i][k] * u[k][h].  One wave per node.
// ---------------------------------------------------------------------------
__global__ __launch_bounds__(256) void proj128_kernel(
    const bf16* __restrict__ x, const bf16* __restrict__ u,
    float4* __restrict__ p, int N)
{
  const int node = (int)(((unsigned)blockIdx.x * 256u + threadIdx.x) >> 6);
  if (node >= N) return;
  const int lane = threadIdx.x & 63;
  const unsigned xv = ((const unsigned*)(x + (size_t)node * 128))[lane];
  const float d0 = bflo(xv), d1 = bfhi(xv);
  const uint4 uv = *(const uint4*)(u + (size_t)lane * 8);
  float t0 = d0 * bflo(uv.x) + d1 * bflo(uv.z);
  float t1 = d0 * bfhi(uv.x) + d1 * bfhi(uv.z);
  float t2 = d0 * bflo(uv.y) + d1 * bflo(uv.w);
  float t3 = d0 * bfhi(uv.y) + d1 * bfhi(uv.w);
  #pragma unroll
  for (int off = 32; off > 0; off >>= 1) {
    t0 += __shfl_xor(t0, off);
    t1 += __shfl_xor(t1, off);
    t2 += __shfl_xor(t2, off);
    t3 += __shfl_xor(t3, off);
  }
  if (lane == 0) p[node] = make_float4(t0, t1, t2, t3);
}

__global__ __launch_bounds__(256) void proj256_kernel(
    const bf16* __restrict__ h, const bf16* __restrict__ u,
    float4* __restrict__ p, int N)
{
  const int node = (int)(((unsigned)blockIdx.x * 256u + threadIdx.x) >> 6);
  if (node >= N) return;
  const int lane = threadIdx.x & 63;
  const uint2 hv = *(const uint2*)(h + (size_t)node * 256 + lane * 4);
  const float d0 = bflo(hv.x), d1 = bfhi(hv.x);
  const float d2 = bflo(hv.y), d3 = bfhi(hv.y);
  const uint4 ua = *(const uint4*)(u + (size_t)lane * 16);
  const uint4 ub = *(const uint4*)(u + (size_t)lane * 16 + 8);
  float t0 = d0*bflo(ua.x) + d1*bflo(ua.z) + d2*bflo(ub.x) + d3*bflo(ub.z);
  float t1 = d0*bfhi(ua.x) + d1*bfhi(ua.z) + d2*bfhi(ub.x) + d3*bfhi(ub.z);
  float t2 = d0*bflo(ua.y) + d1*bflo(ua.w) + d2*bflo(ub.y) + d3*bflo(ub.w);
  float t3 = d0*bfhi(ua.y) + d1*bfhi(ua.w) + d2*bfhi(ub.y) + d3*bfhi(ub.w);
  #pragma unroll
  for (int off = 32; off > 0; off >>= 1) {
    t0 += __shfl_xor(t0, off);
    t1 += __shfl_xor(t1, off);
    t2 += __shfl_xor(t2, off);
    t3 += __shfl_xor(t3, off);
  }
  if (lane == 0) p[node] = make_float4(t0, t1, t2, t3);
}

// ---------------------------------------------------------------------------
// Pass A: per sorted edge, q = softmax(p[src] - p[dst] + c). Thread per edge.
// ---------------------------------------------------------------------------
__global__ __launch_bounds__(256) void passA_kernel(
    const float4* __restrict__ p, const int* __restrict__ ssrc,
    const int* __restrict__ sdst, const bf16* __restrict__ cvec,
    float4* __restrict__ qs, int E)
{
  const int e = (int)((unsigned)blockIdx.x * 256u + threadIdx.x);
  if (e >= E) return;
  const float4 ps = p[ssrc[e]];
  const float4 pd = p[sdst[e]];
  const float t0 = ps.x - pd.x + __bfloat162float(cvec[0]);
  const float t1 = ps.y - pd.y + __bfloat162float(cvec[1]);
  const float t2 = ps.z - pd.z + __bfloat162float(cvec[2]);
  const float t3 = ps.w - pd.w + __bfloat162float(cvec[3]);
  const float mx = fmaxf(fmaxf(t0, t1), fmaxf(t2, t3));
  const float e0 = __expf(t0 - mx), e1 = __expf(t1 - mx);
  const float e2 = __expf(t2 - mx), e3 = __expf(t3 - mx);
  const float inv = 1.f / (e0 + e1 + e2 + e3);
  qs[e] = make_float4(e0 * inv, e1 * inv, e2 * inv, e3 * inv);
}

// ---------------------------------------------------------------------------
// Pass B: one block per dst node, thread = output channel. y is fp8
// head-interleaved [node][channel][head] -> one uint (4 fp8) per edge.
// ---------------------------------------------------------------------------
template<bool OUT_FLOAT, bool SKIP_FLOAT>
__global__ __launch_bounds__(256) void passB_kernel(
    const int* __restrict__ rowptr, const int* __restrict__ ssrc,
    const float4* __restrict__ qs, const unsigned char* __restrict__ y,
    const bf16* __restrict__ cvec, const bf16* __restrict__ bias,
    const float* __restrict__ skipf, const bf16* __restrict__ skipb,
    float* __restrict__ outf, bf16* __restrict__ outb)
{
  const int i = blockIdx.x;
  const int k = threadIdx.x;
  const int beg = rowptr[i], end = rowptr[i + 1];

  float acc = 0.f;
  for (int e = beg; e < end; ++e) {
    const int src = ssrc[e];
    const float4 q = qs[e];
    const unsigned v = *(const unsigned*)(y + (size_t)src * 1024 + k * 4);
    const f32x2 lo = __builtin_amdgcn_cvt_pk_f32_fp8((int)v, false);
    const f32x2 hi = __builtin_amdgcn_cvt_pk_f32_fp8((int)v, true);
    acc += q.x * lo.x + q.y * lo.y + q.z * hi.x + q.w * hi.y;
  }

  const float c0 = __bfloat162float(cvec[0]), c1 = __bfloat162float(cvec[1]);
  const float c2 = __bfloat162float(cvec[2]), c3 = __bfloat162float(cvec[3]);
  const float mx = fmaxf(fmaxf(c0, c1), fmaxf(c2, c3));
  const float e0 = __expf(c0 - mx), e1 = __expf(c1 - mx);
  const float e2 = __expf(c2 - mx), e3 = __expf(c3 - mx);
  const float inv = 1.f / (e0 + e1 + e2 + e3);
  const unsigned vi = *(const unsigned*)(y + (size_t)i * 1024 + k * 4);
  const f32x2 li = __builtin_amdgcn_cvt_pk_f32_fp8((int)vi, false);
  const f32x2 hii = __builtin_amdgcn_cvt_pk_f32_fp8((int)vi, true);
  acc += (e0 * li.x + e1 * li.y + e2 * hii.x + e3 * hii.y) * inv;

  const int idx = i * 256 + k;
  float v = acc / (float)(end - beg + 1) + __bfloat162float(bias[k]);
  v += SKIP_FLOAT ? skipf[idx] : __bfloat162float(skipb[idx]);
  v = fmaxf(v, 0.f);
  if (OUT_FLOAT) outf[idx] = v;
  else           outb[idx] = __float2bfloat16(v);
}

// Output 1: edge_index values written as float32
__global__ __launch_bounds__(256) void edgecopy_kernel(
    const int* __restrict__ ei, float* __restrict__ out, int n)
{
  const int i = (int)((unsigned)blockIdx.x * 256u + threadIdx.x);
  if (i < n) out[i] = (float)ei[i];
}

extern "C" void kernel_launch(void* const* d_in, const int* in_sizes, int n_in,
                              void* d_out, int out_size, void* d_ws, size_t ws_size,
                              hipStream_t stream)
{
  const bf16* x   = (const bf16*)d_in[0];
  const int*  ei  = (const int*)d_in[1];
  const bf16* W0  = (const bf16*)d_in[2];
  const bf16* u0  = (const bf16*)d_in[3];
  const bf16* c0  = (const bf16*)d_in[4];
  const bf16* b0  = (const bf16*)d_in[5];
  const bf16* sW0 = (const bf16*)d_in[6];
  const bf16* sb0 = (const bf16*)d_in[7];
  const bf16* W1  = (const bf16*)d_in[8];
  const bf16* u1  = (const bf16*)d_in[9];
  const bf16* c1  = (const bf16*)d_in[10];
  const bf16* b1  = (const bf16*)d_in[11];

  const int N = in_sizes[0] / 128;   // 20000
  const int E = in_sizes[1] / 2;     // 320000

  // workspace layout (~64 MB)
  char* ws = (char*)d_ws;
  unsigned char* y = (unsigned char*)ws; ws += (size_t)N * 1024;        // fp8, head-interleaved
  float*  skip0  = (float*)ws;  ws += (size_t)N * 256 * sizeof(float);
  bf16*   h0     = (bf16*)ws;   ws += (size_t)N * 256 * sizeof(bf16);
  float4* qs     = (float4*)ws; ws += (size_t)E * sizeof(float4);
  float4* p      = (float4*)ws; ws += (size_t)N * sizeof(float4);
  int*    ssrc   = (int*)ws;    ws += (size_t)E * sizeof(int);
  int*    sdst   = (int*)ws;    ws += (size_t)E * sizeof(int);
  int*    deg    = (int*)ws;    ws += (size_t)N * sizeof(int);
  int*    cursor = (int*)ws;    ws += (size_t)N * sizeof(int);
  int*    rowptr = (int*)ws;    ws += ((size_t)N + 1) * sizeof(int);
  bf16*   Bt0    = (bf16*)ws;   ws += (size_t)1280 * 128 * sizeof(bf16); // [W0|sW0]^T
  bf16*   Bt1    = (bf16*)ws;   ws += (size_t)1024 * 256 * sizeof(bf16); // W1^T

  hipMemsetAsync(deg, 0, 2 * (size_t)N * sizeof(int), stream);  // deg + cursor

  const int eBlocks = (E + 255) / 256;
  const int nwBlocks = (N * 64 + 255) / 256;   // wave-per-node kernels
  const int mTiles  = (N + 127) / 128;

  // ---- weight transposes ----
  transpose_kernel<<<dim3(1024/32, 128/32), 256, 0, stream>>>(W0,  Bt0,               128, 1024);
  transpose_kernel<<<dim3( 256/32, 128/32), 256, 0, stream>>>(sW0, Bt0 + 1024 * 128,  128,  256);
  transpose_kernel<<<dim3(1024/32, 256/32), 256, 0, stream>>>(W1,  Bt1,               256, 1024);

  // ---- sort edges by dst ----
  hist_kernel<<<eBlocks, 256, 0, stream>>>(ei, deg, E);
  scan_kernel<<<1, 256, 0, stream>>>(deg, rowptr, N);
  scatter_kernel<<<eBlocks, 256, 0, stream>>>(ei, rowptr, cursor, ssrc, sdst, E);

  // ---- Block 0 ----
  proj128_kernel<<<nwBlocks, 256, 0, stream>>>(x, u0, p, N);
  gemm_mfma_kernel<<<dim3(mTiles, 10), 256, 0, stream>>>(
      x, Bt0, N, 128, y, 1024, skip0, sb0, 256);
  passA_kernel<<<eBlocks, 256, 0, stream>>>(p, ssrc, sdst, c0, qs, E);
  passB_kernel<false, true><<<N, 256, 0, stream>>>(rowptr, ssrc, qs, y, c0, b0,
                                                   skip0, nullptr, nullptr, h0);

  // ---- Block 1 ----
  proj256_kernel<<<nwBlocks, 256, 0, stream>>>(h0, u1, p, N);
  gemm_mfma_kernel<<<dim3(mTiles, 8), 256, 0, stream>>>(
      h0, Bt1, N, 256, y, 1024, nullptr, nullptr, 256);
  passA_kernel<<<eBlocks, 256, 0, stream>>>(p, ssrc, sdst, c1, qs, E);
  passB_kernel<true, false><<<N, 256, 0, stream>>>(rowptr, ssrc, qs, y, c1, b1,
                                                   nullptr, h0, (float*)d_out, nullptr);

  // ---- Output 1: edge_index ----
  edgecopy_kernel<<<(2 * E + 255) / 256, 256, 0, stream>>>(
      ei, (float*)d_out + (size_t)N * 256, 2 * E);
}

// Round 7
// 354.444 us; speedup vs baseline: 7.1363x; 1.1675x over previous
//
#include <hip/hip_runtime.h>
#include <hip/hip_bf16.h>

typedef __hip_bfloat16 bf16;

typedef short bf16x8 __attribute__((ext_vector_type(8)));   // 8 bf16 (4 VGPRs), MFMA A/B frag
typedef float f32x4  __attribute__((ext_vector_type(4)));   // MFMA C/D frag
typedef float f32x2  __attribute__((ext_vector_type(2)));

__device__ __forceinline__ float bflo(unsigned v){ union{unsigned u; float f;} c; c.u = v << 16; return c.f; }
__device__ __forceinline__ float bfhi(unsigned v){ union{unsigned u; float f;} c; c.u = v & 0xffff0000u; return c.f; }

// float -> fp8 e4m3 (OCP on gfx950), single byte
__device__ __forceinline__ unsigned char f32_to_fp8(float v){
  return (unsigned char)(__builtin_amdgcn_cvt_pk_fp8_f32(v, v, 0, false) & 0xFF);
}

// ---------------------------------------------------------------------------
// Weight transpose: B[K][NC] -> Bt[NC][K]. LDS 32x33 tile. K,NC multiples of 32.
// ---------------------------------------------------------------------------
__global__ __launch_bounds__(256) void transpose_kernel(
    const bf16* __restrict__ B, bf16* __restrict__ Bt, int K, int NC)
{
  __shared__ bf16 t[32][33];
  const int bx = blockIdx.x;            // along NC
  const int by = blockIdx.y;            // along K
  const int tx = threadIdx.x & 31, ty = threadIdx.x >> 5;  // ty 0..7
  #pragma unroll
  for (int i = 0; i < 32; i += 8)
    t[ty + i][tx] = B[(size_t)(by * 32 + ty + i) * NC + bx * 32 + tx];
  __syncthreads();
  #pragma unroll
  for (int i = 0; i < 32; i += 8)
    Bt[(size_t)(bx * 32 + ty + i) * K + by * 32 + tx] = t[tx][ty + i];
}

// ---------------------------------------------------------------------------
// MFMA GEMM: C[M x NC] = A[M x K](bf16, row-major) @ Bt[NC x K](bf16, n-major)
// 128x128 block tile, 4 waves (2x2), each wave 4x4 of 16x16x32 MFMA, BK=32.
// col0 <  nsplit -> fp8 byte store to Cy, HEAD-INTERLEAVED:
//                   Cy[row*1024 + (col&255)*4 + (col>>8)]   (y[node][ch][head])
// col0 >= nsplit -> f32 store to Cs (ld=lds_) + bias (normal layout).
// ---------------------------------------------------------------------------
__global__ __launch_bounds__(256) void gemm_mfma_kernel(
    const bf16* __restrict__ A, const bf16* __restrict__ Bt,
    int M, int K,
    unsigned char* __restrict__ Cy, int nsplit,
    float* __restrict__ Cs, const bf16* __restrict__ sbias, int lds_)
{
  constexpr int LDA = 40;                       // padded LDS row stride (bf16 elems), 80B
  __shared__ __align__(16) bf16 As[128 * LDA];  // 10240 B
  __shared__ __align__(16) bf16 Bs[128 * LDA];  // 10240 B

  const int tid  = threadIdx.x;
  const int row0 = blockIdx.x * 128;
  const int col0 = blockIdx.y * 128;
  const int lane = tid & 63;
  const int wave = tid >> 6;
  const int wm   = wave & 1, wn = wave >> 1;
  const int ln   = lane & 15, quad = lane >> 4;

  f32x4 acc[4][4] = {};

  for (int k0 = 0; k0 < K; k0 += 32) {
    #pragma unroll
    for (int rep = 0; rep < 2; ++rep) {
      const int cs = tid + rep * 256;
      const int r  = cs >> 2;
      const int kp = (cs & 3) << 3;
      const int gr = min(row0 + r, M - 1);      // clamp: dup rows only feed unstored C rows
      const uint4 va = *(const uint4*)(A  + (size_t)gr * K        + k0 + kp);
      *(uint4*)(As + r * LDA + kp) = va;
      const uint4 vb = *(const uint4*)(Bt + (size_t)(col0 + r) * K + k0 + kp);
      *(uint4*)(Bs + r * LDA + kp) = vb;
    }
    __syncthreads();

    bf16x8 a[4], b[4];
    #pragma unroll
    for (int mi = 0; mi < 4; ++mi)
      a[mi] = *(const bf16x8*)(As + (wm * 64 + mi * 16 + ln) * LDA + quad * 8);
    #pragma unroll
    for (int ni = 0; ni < 4; ++ni)
      b[ni] = *(const bf16x8*)(Bs + (wn * 64 + ni * 16 + ln) * LDA + quad * 8);
    #pragma unroll
    for (int mi = 0; mi < 4; ++mi)
      #pragma unroll
      for (int ni = 0; ni < 4; ++ni)
        acc[mi][ni] = __builtin_amdgcn_mfma_f32_16x16x32_bf16(a[mi], b[ni], acc[mi][ni], 0, 0, 0);
    __syncthreads();
  }

  // epilogue: C[row=quad*4+r][col=ln] per 16x16 tile
  if (col0 < nsplit) {
    #pragma unroll
    for (int mi = 0; mi < 4; ++mi) {
      const int rbase = row0 + wm * 64 + mi * 16 + quad * 4;
      #pragma unroll
      for (int ni = 0; ni < 4; ++ni) {
        const int col = col0 + wn * 64 + ni * 16 + ln;
        const int ic  = (col & 255) * 4 + (col >> 8);   // head-interleaved byte position
        #pragma unroll
        for (int r = 0; r < 4; ++r) {
          const int gr = rbase + r;
          if (gr < M) Cy[(size_t)gr * 1024 + ic] = f32_to_fp8(acc[mi][ni][r]);
        }
      }
    }
  } else {
    const int cbase = col0 - nsplit;
    #pragma unroll
    for (int mi = 0; mi < 4; ++mi) {
      const int rbase = row0 + wm * 64 + mi * 16 + quad * 4;
      #pragma unroll
      for (int ni = 0; ni < 4; ++ni) {
        const int col = cbase + wn * 64 + ni * 16 + ln;
        const float bb = __bfloat162float(sbias[col]);
        #pragma unroll
        for (int r = 0; r < 4; ++r) {
          const int gr = rbase + r;
          if (gr < M) Cs[(size_t)gr * lds_ + col] = acc[mi][ni][r] + bb;
        }
      }
    }
  }
}

// ---------------------------------------------------------------------------
// Edge sorting by dst: histogram -> single-block scan -> scatter
// ---------------------------------------------------------------------------
__global__ __launch_bounds__(256) void hist_kernel(
    const int* __restrict__ ei, int* __restrict__ deg, int E)
{
  const int e = (int)((unsigned)blockIdx.x * 256u + threadIdx.x);
  if (e < E) atomicAdd(deg + ei[E + e], 1);
}

__global__ __launch_bounds__(256) void scan_kernel(
    const int* __restrict__ deg, int* __restrict__ rowptr, int N)
{
  __shared__ int part[256];
  const int t = threadIdx.x;
  const int chunk = (N + 255) / 256;
  const int start = t * chunk;
  const int stop  = min(start + chunk, N);
  int sum = 0;
  for (int j = start; j < stop; ++j) sum += deg[j];
  part[t] = sum;
  __syncthreads();
  for (int off = 1; off < 256; off <<= 1) {
    int v = (t >= off) ? part[t - off] : 0;
    __syncthreads();
    part[t] += v;
    __syncthreads();
  }
  int base = (t == 0) ? 0 : part[t - 1];
  for (int j = start; j < stop; ++j) { rowptr[j] = base; base += deg[j]; }
  if (t == 255) rowptr[N] = part[255];
}

__global__ __launch_bounds__(256) void scatter_kernel(
    const int* __restrict__ ei, const int* __restrict__ rowptr,
    int* __restrict__ cursor, int* __restrict__ ssrc, int* __restrict__ sdst, int E)
{
  const int e = (int)((unsigned)blockIdx.x * 256u + threadIdx.x);
  if (e >= E) return;
  const int src = ei[e];
  const int d   = ei[E + e];
  const int p   = rowptr[d] + atomicAdd(cursor + d, 1);
  ssrc[p] = src;
  sdst[p] = d;
}

// ---------------------------------------------------------------------------
// Projection: p[i][h] = sum_k feat[i][k] * u[k][h].  One wave per node.
// ---------------------------------------------------------------------------
__global__ __launch_bounds__(256) void proj128_kernel(
    const bf16* __restrict__ x, const bf16* __restrict__ u,
    float4* __restrict__ p, int N)
{
  const int node = (int)(((unsigned)blockIdx.x * 256u + threadIdx.x) >> 6);
  if (node >= N) return;
  const int lane = threadIdx.x & 63;
  const unsigned xv = ((const unsigned*)(x + (size_t)node * 128))[lane];
  const float d0 = bflo(xv), d1 = bfhi(xv);
  const uint4 uv = *(const uint4*)(u + (size_t)lane * 8);
  float t0 = d0 * bflo(uv.x) + d1 * bflo(uv.z);
  float t1 = d0 * bfhi(uv.x) + d1 * bfhi(uv.z);
  float t2 = d0 * bflo(uv.y) + d1 * bflo(uv.w);
  float t3 = d0 * bfhi(uv.y) + d1 * bfhi(uv.w);
  #pragma unroll
  for (int off = 32; off > 0; off >>= 1) {
    t0 += __shfl_xor(t0, off);
    t1 += __shfl_xor(t1, off);
    t2 += __shfl_xor(t2, off);
    t3 += __shfl_xor(t3, off);
  }
  if (lane == 0) p[node] = make_float4(t0, t1, t2, t3);
}

__global__ __launch_bounds__(256) void proj256_kernel(
    const bf16* __restrict__ h, const bf16* __restrict__ u,
    float4* __restrict__ p, int N)
{
  const int node = (int)(((unsigned)blockIdx.x * 256u + threadIdx.x) >> 6);
  if (node >= N) return;
  const int lane = threadIdx.x & 63;
  const uint2 hv = *(const uint2*)(h + (size_t)node * 256 + lane * 4);
  const float d0 = bflo(hv.x), d1 = bfhi(hv.x);
  const float d2 = bflo(hv.y), d3 = bfhi(hv.y);
  const uint4 ua = *(const uint4*)(u + (size_t)lane * 16);
  const uint4 ub = *(const uint4*)(u + (size_t)lane * 16 + 8);
  float t0 = d0*bflo(ua.x) + d1*bflo(ua.z) + d2*bflo(ub.x) + d3*bflo(ub.z);
  float t1 = d0*bfhi(ua.x) + d1*bfhi(ua.z) + d2*bfhi(ub.x) + d3*bfhi(ub.z);
  float t2 = d0*bflo(ua.y) + d1*bflo(ua.w) + d2*bflo(ub.y) + d3*bflo(ub.w);
  float t3 = d0*bfhi(ua.y) + d1*bfhi(ua.w) + d2*bfhi(ub.y) + d3*bfhi(ub.w);
  #pragma unroll
  for (int off = 32; off > 0; off >>= 1) {
    t0 += __shfl_xor(t0, off);
    t1 += __shfl_xor(t1, off);
    t2 += __shfl_xor(t2, off);
    t3 += __shfl_xor(t3, off);
  }
  if (lane == 0) p[node] = make_float4(t0, t1, t2, t3);
}

// ---------------------------------------------------------------------------
// Pass A: per sorted edge, q = softmax(p[src] - p[dst] + c). Thread per edge.
// ---------------------------------------------------------------------------
__global__ __launch_bounds__(256) void passA_kernel(
    const float4* __restrict__ p, const int* __restrict__ ssrc,
    const int* __restrict__ sdst, const bf16* __restrict__ cvec,
    float4* __restrict__ qs, int E)
{
  const int e = (int)((unsigned)blockIdx.x * 256u + threadIdx.x);
  if (e >= E) return;
  const float4 ps = p[ssrc[e]];
  const float4 pd = p[sdst[e]];
  const float t0 = ps.x - pd.x + __bfloat162float(cvec[0]);
  const float t1 = ps.y - pd.y + __bfloat162float(cvec[1]);
  const float t2 = ps.z - pd.z + __bfloat162float(cvec[2]);
  const float t3 = ps.w - pd.w + __bfloat162float(cvec[3]);
  const float mx = fmaxf(fmaxf(t0, t1), fmaxf(t2, t3));
  const float e0 = __expf(t0 - mx), e1 = __expf(t1 - mx);
  const float e2 = __expf(t2 - mx), e3 = __expf(t3 - mx);
  const float inv = 1.f / (e0 + e1 + e2 + e3);
  qs[e] = make_float4(e0 * inv, e1 * inv, e2 * inv, e3 * inv);
}

// ---------------------------------------------------------------------------
// Pass B: one block per dst node, thread = output channel. y is fp8
// head-interleaved [node][channel][head] -> one uint (4 fp8) per edge.
// v3: (src,q) staged in LDS per 64-edge chunk; edge loop unrolled x4 so
// >=4 independent y-gathers are in flight (latency hiding, G7).
// ---------------------------------------------------------------------------
#define PB_CHUNK 64

template<bool OUT_FLOAT, bool SKIP_FLOAT>
__global__ __launch_bounds__(256) void passB_kernel(
    const int* __restrict__ rowptr, const int* __restrict__ ssrc,
    const float4* __restrict__ qs, const unsigned char* __restrict__ y,
    const bf16* __restrict__ cvec, const bf16* __restrict__ bias,
    const float* __restrict__ skipf, const bf16* __restrict__ skipb,
    float* __restrict__ outf, bf16* __restrict__ outb)
{
  __shared__ int    s_src[PB_CHUNK];
  __shared__ float4 s_q[PB_CHUNK];

  const int i = blockIdx.x;
  const int k = threadIdx.x;
  const int beg = rowptr[i], end = rowptr[i + 1];
  const int deg = end - beg;

  float acc = 0.f;
  for (int c0 = 0; c0 < deg; c0 += PB_CHUNK) {
    const int cnt = min(PB_CHUNK, deg - c0);
    __syncthreads();
    if (k < cnt) {
      s_src[k] = ssrc[beg + c0 + k];
      s_q[k]   = qs[beg + c0 + k];
    }
    __syncthreads();

    int e = 0;
    for (; e + 4 <= cnt; e += 4) {
      const unsigned v0 = *(const unsigned*)(y + (size_t)s_src[e    ] * 1024 + k * 4);
      const unsigned v1 = *(const unsigned*)(y + (size_t)s_src[e + 1] * 1024 + k * 4);
      const unsigned v2 = *(const unsigned*)(y + (size_t)s_src[e + 2] * 1024 + k * 4);
      const unsigned v3 = *(const unsigned*)(y + (size_t)s_src[e + 3] * 1024 + k * 4);
      const float4 q0 = s_q[e], q1 = s_q[e + 1], q2 = s_q[e + 2], q3 = s_q[e + 3];
      {
        const f32x2 lo = __builtin_amdgcn_cvt_pk_f32_fp8((int)v0, false);
        const f32x2 hi = __builtin_amdgcn_cvt_pk_f32_fp8((int)v0, true);
        acc += q0.x * lo.x + q0.y * lo.y + q0.z * hi.x + q0.w * hi.y;
      }
      {
        const f32x2 lo = __builtin_amdgcn_cvt_pk_f32_fp8((int)v1, false);
        const f32x2 hi = __builtin_amdgcn_cvt_pk_f32_fp8((int)v1, true);
        acc += q1.x * lo.x + q1.y * lo.y + q1.z * hi.x + q1.w * hi.y;
      }
      {
        const f32x2 lo = __builtin_amdgcn_cvt_pk_f32_fp8((int)v2, false);
        const f32x2 hi = __builtin_amdgcn_cvt_pk_f32_fp8((int)v2, true);
        acc += q2.x * lo.x + q2.y * lo.y + q2.z * hi.x + q2.w * hi.y;
      }
      {
        const f32x2 lo = __builtin_amdgcn_cvt_pk_f32_fp8((int)v3, false);
        const f32x2 hi = __builtin_amdgcn_cvt_pk_f32_fp8((int)v3, true);
        acc += q3.x * lo.x + q3.y * lo.y + q3.z * hi.x + q3.w * hi.y;
      }
    }
    for (; e < cnt; ++e) {
      const unsigned v = *(const unsigned*)(y + (size_t)s_src[e] * 1024 + k * 4);
      const float4 q = s_q[e];
      const f32x2 lo = __builtin_amdgcn_cvt_pk_f32_fp8((int)v, false);
      const f32x2 hi = __builtin_amdgcn_cvt_pk_f32_fp8((int)v, true);
      acc += q.x * lo.x + q.y * lo.y + q.z * hi.x + q.w * hi.y;
    }
  }

  const float c0 = __bfloat162float(cvec[0]), c1 = __bfloat162float(cvec[1]);
  const float c2 = __bfloat162float(cvec[2]), c3 = __bfloat162float(cvec[3]);
  const float mx = fmaxf(fmaxf(c0, c1), fmaxf(c2, c3));
  const float e0 = __expf(c0 - mx), e1 = __expf(c1 - mx);
  const float e2 = __expf(c2 - mx), e3 = __expf(c3 - mx);
  const float inv = 1.f / (e0 + e1 + e2 + e3);
  const unsigned vi = *(const unsigned*)(y + (size_t)i * 1024 + k * 4);
  const f32x2 li  = __builtin_amdgcn_cvt_pk_f32_fp8((int)vi, false);
  const f32x2 hii = __builtin_amdgcn_cvt_pk_f32_fp8((int)vi, true);
  acc += (e0 * li.x + e1 * li.y + e2 * hii.x + e3 * hii.y) * inv;

  const int idx = i * 256 + k;
  float v = acc / (float)(deg + 1) + __bfloat162float(bias[k]);
  v += SKIP_FLOAT ? skipf[idx] : __bfloat162float(skipb[idx]);
  v = fmaxf(v, 0.f);
  if (OUT_FLOAT) outf[idx] = v;
  else           outb[idx] = __float2bfloat16(v);
}

// Output 1: edge_index values written as float32
__global__ __launch_bounds__(256) void edgecopy_kernel(
    const int* __restrict__ ei, float* __restrict__ out, int n)
{
  const int i = (int)((unsigned)blockIdx.x * 256u + threadIdx.x);
  if (i < n) out[i] = (float)ei[i];
}

extern "C" void kernel_launch(void* const* d_in, const int* in_sizes, int n_in,
                              void* d_out, int out_size, void* d_ws, size_t ws_size,
                              hipStream_t stream)
{
  const bf16* x   = (const bf16*)d_in[0];
  const int*  ei  = (const int*)d_in[1];
  const bf16* W0  = (const bf16*)d_in[2];
  const bf16* u0  = (const bf16*)d_in[3];
  const bf16* c0  = (const bf16*)d_in[4];
  const bf16* b0  = (const bf16*)d_in[5];
  const bf16* sW0 = (const bf16*)d_in[6];
  const bf16* sb0 = (const bf16*)d_in[7];
  const bf16* W1  = (const bf16*)d_in[8];
  const bf16* u1  = (const bf16*)d_in[9];
  const bf16* c1  = (const bf16*)d_in[10];
  const bf16* b1  = (const bf16*)d_in[11];

  const int N = in_sizes[0] / 128;   // 20000
  const int E = in_sizes[1] / 2;     // 320000

  // workspace layout (~64 MB)
  char* ws = (char*)d_ws;
  unsigned char* y = (unsigned char*)ws; ws += (size_t)N * 1024;        // fp8, head-interleaved
  float*  skip0  = (float*)ws;  ws += (size_t)N * 256 * sizeof(float);
  bf16*   h0     = (bf16*)ws;   ws += (size_t)N * 256 * sizeof(bf16);
  float4* qs     = (float4*)ws; ws += (size_t)E * sizeof(float4);
  float4* p      = (float4*)ws; ws += (size_t)N * sizeof(float4);
  int*    ssrc   = (int*)ws;    ws += (size_t)E * sizeof(int);
  int*    sdst   = (int*)ws;    ws += (size_t)E * sizeof(int);
  int*    deg    = (int*)ws;    ws += (size_t)N * sizeof(int);
  int*    cursor = (int*)ws;    ws += (size_t)N * sizeof(int);
  int*    rowptr = (int*)ws;    ws += ((size_t)N + 1) * sizeof(int);
  bf16*   Bt0    = (bf16*)ws;   ws += (size_t)1280 * 128 * sizeof(bf16); // [W0|sW0]^T
  bf16*   Bt1    = (bf16*)ws;   ws += (size_t)1024 * 256 * sizeof(bf16); // W1^T

  hipMemsetAsync(deg, 0, 2 * (size_t)N * sizeof(int), stream);  // deg + cursor

  const int eBlocks = (E + 255) / 256;
  const int nwBlocks = (N * 64 + 255) / 256;   // wave-per-node kernels
  const int mTiles  = (N + 127) / 128;

  // ---- weight transposes ----
  transpose_kernel<<<dim3(1024/32, 128/32), 256, 0, stream>>>(W0,  Bt0,               128, 1024);
  transpose_kernel<<<dim3( 256/32, 128/32), 256, 0, stream>>>(sW0, Bt0 + 1024 * 128,  128,  256);
  transpose_kernel<<<dim3(1024/32, 256/32), 256, 0, stream>>>(W1,  Bt1,               256, 1024);

  // ---- sort edges by dst ----
  hist_kernel<<<eBlocks, 256, 0, stream>>>(ei, deg, E);
  scan_kernel<<<1, 256, 0, stream>>>(deg, rowptr, N);
  scatter_kernel<<<eBlocks, 256, 0, stream>>>(ei, rowptr, cursor, ssrc, sdst, E);

  // ---- Block 0 ----
  proj128_kernel<<<nwBlocks, 256, 0, stream>>>(x, u0, p, N);
  gemm_mfma_kernel<<<dim3(mTiles, 10), 256, 0, stream>>>(
      x, Bt0, N, 128, y, 1024, skip0, sb0, 256);
  passA_kernel<<<eBlocks, 256, 0, stream>>>(p, ssrc, sdst, c0, qs, E);
  passB_kernel<false, true><<<N, 256, 0, stream>>>(rowptr, ssrc, qs, y, c0, b0,
                                                   skip0, nullptr, nullptr, h0);

  // ---- Block 1 ----
  proj256_kernel<<<nwBlocks, 256, 0, stream>>>(h0, u1, p, N);
  gemm_mfma_kernel<<<dim3(mTiles, 8), 256, 0, stream>>>(
      h0, Bt1, N, 256, y, 1024, nullptr, nullptr, 256);
  passA_kernel<<<eBlocks, 256, 0, stream>>>(p, ssrc, sdst, c1, qs, E);
  passB_kernel<true, false><<<N, 256, 0, stream>>>(rowptr, ssrc, qs, y, c1, b1,
                                                   nullptr, h0, (float*)d_out, nullptr);

  // ---- Output 1: edge_index ----
  edgecopy_kernel<<<(2 * E + 255) / 256, 256, 0, stream>>>(
      ei, (float*)d_out + (size_t)N * 256, 2 * E);
}

// Round 8
// 347.331 us; speedup vs baseline: 7.2825x; 1.0205x over previous
//
#include <hip/hip_runtime.h>
#include <hip/hip_bf16.h>

typedef __hip_bfloat16 bf16;

typedef short bf16x8 __attribute__((ext_vector_type(8)));   // 8 bf16 (4 VGPRs), MFMA A/B frag
typedef float f32x4  __attribute__((ext_vector_type(4)));   // MFMA C/D frag
typedef float f32x2  __attribute__((ext_vector_type(2)));

__device__ __forceinline__ float bflo(unsigned v){ union{unsigned u; float f;} c; c.u = v << 16; return c.f; }
__device__ __forceinline__ float bfhi(unsigned v){ union{unsigned u; float f;} c; c.u = v & 0xffff0000u; return c.f; }

// float -> fp8 e4m3 (OCP on gfx950), single byte
__device__ __forceinline__ unsigned char f32_to_fp8(float v){
  return (unsigned char)(__builtin_amdgcn_cvt_pk_fp8_f32(v, v, 0, false) & 0xFF);
}

// ---------------------------------------------------------------------------
// Weight transpose: B[K][NC] -> Bt[NC][K]. LDS 32x33 tile. K,NC multiples of 32.
// ---------------------------------------------------------------------------
__global__ __launch_bounds__(256) void transpose_kernel(
    const bf16* __restrict__ B, bf16* __restrict__ Bt, int K, int NC)
{
  __shared__ bf16 t[32][33];
  const int bx = blockIdx.x;            // along NC
  const int by = blockIdx.y;            // along K
  const int tx = threadIdx.x & 31, ty = threadIdx.x >> 5;  // ty 0..7
  #pragma unroll
  for (int i = 0; i < 32; i += 8)
    t[ty + i][tx] = B[(size_t)(by * 32 + ty + i) * NC + bx * 32 + tx];
  __syncthreads();
  #pragma unroll
  for (int i = 0; i < 32; i += 8)
    Bt[(size_t)(bx * 32 + ty + i) * K + by * 32 + tx] = t[tx][ty + i];
}

// ---------------------------------------------------------------------------
// MFMA GEMM: C[M x NC] = A[M x K](bf16, row-major) @ Bt[NC x K](bf16, n-major)
// 128x128 block tile, 4 waves (2x2), each wave 4x4 of 16x16x32 MFMA, BK=32.
// col0 <  nsplit -> fp8 byte store to Cy, HEAD-INTERLEAVED:
//                   Cy[row*1024 + (col&255)*4 + (col>>8)]   (y[node][ch][head])
// col0 >= nsplit -> f32 store to Cs (ld=lds_) + bias (normal layout).
// ---------------------------------------------------------------------------
__global__ __launch_bounds__(256) void gemm_mfma_kernel(
    const bf16* __restrict__ A, const bf16* __restrict__ Bt,
    int M, int K,
    unsigned char* __restrict__ Cy, int nsplit,
    float* __restrict__ Cs, const bf16* __restrict__ sbias, int lds_)
{
  constexpr int LDA = 40;                       // padded LDS row stride (bf16 elems), 80B
  __shared__ __align__(16) bf16 As[128 * LDA];  // 10240 B
  __shared__ __align__(16) bf16 Bs[128 * LDA];  // 10240 B

  const int tid  = threadIdx.x;
  const int row0 = blockIdx.x * 128;
  const int col0 = blockIdx.y * 128;
  const int lane = tid & 63;
  const int wave = tid >> 6;
  const int wm   = wave & 1, wn = wave >> 1;
  const int ln   = lane & 15, quad = lane >> 4;

  f32x4 acc[4][4] = {};

  for (int k0 = 0; k0 < K; k0 += 32) {
    #pragma unroll
    for (int rep = 0; rep < 2; ++rep) {
      const int cs = tid + rep * 256;
      const int r  = cs >> 2;
      const int kp = (cs & 3) << 3;
      const int gr = min(row0 + r, M - 1);      // clamp: dup rows only feed unstored C rows
      const uint4 va = *(const uint4*)(A  + (size_t)gr * K        + k0 + kp);
      *(uint4*)(As + r * LDA + kp) = va;
      const uint4 vb = *(const uint4*)(Bt + (size_t)(col0 + r) * K + k0 + kp);
      *(uint4*)(Bs + r * LDA + kp) = vb;
    }
    __syncthreads();

    bf16x8 a[4], b[4];
    #pragma unroll
    for (int mi = 0; mi < 4; ++mi)
      a[mi] = *(const bf16x8*)(As + (wm * 64 + mi * 16 + ln) * LDA + quad * 8);
    #pragma unroll
    for (int ni = 0; ni < 4; ++ni)
      b[ni] = *(const bf16x8*)(Bs + (wn * 64 + ni * 16 + ln) * LDA + quad * 8);
    #pragma unroll
    for (int mi = 0; mi < 4; ++mi)
      #pragma unroll
      for (int ni = 0; ni < 4; ++ni)
        acc[mi][ni] = __builtin_amdgcn_mfma_f32_16x16x32_bf16(a[mi], b[ni], acc[mi][ni], 0, 0, 0);
    __syncthreads();
  }

  // epilogue: C[row=quad*4+r][col=ln] per 16x16 tile
  if (col0 < nsplit) {
    #pragma unroll
    for (int mi = 0; mi < 4; ++mi) {
      const int rbase = row0 + wm * 64 + mi * 16 + quad * 4;
      #pragma unroll
      for (int ni = 0; ni < 4; ++ni) {
        const int col = col0 + wn * 64 + ni * 16 + ln;
        const int ic  = (col & 255) * 4 + (col >> 8);   // head-interleaved byte position
        #pragma unroll
        for (int r = 0; r < 4; ++r) {
          const int gr = rbase + r;
          if (gr < M) Cy[(size_t)gr * 1024 + ic] = f32_to_fp8(acc[mi][ni][r]);
        }
      }
    }
  } else {
    const int cbase = col0 - nsplit;
    #pragma unroll
    for (int mi = 0; mi < 4; ++mi) {
      const int rbase = row0 + wm * 64 + mi * 16 + quad * 4;
      #pragma unroll
      for (int ni = 0; ni < 4; ++ni) {
        const int col = cbase + wn * 64 + ni * 16 + ln;
        const float bb = __bfloat162float(sbias[col]);
        #pragma unroll
        for (int r = 0; r < 4; ++r) {
          const int gr = rbase + r;
          if (gr < M) Cs[(size_t)gr * lds_ + col] = acc[mi][ni][r] + bb;
        }
      }
    }
  }
}

// ---------------------------------------------------------------------------
// Edge sorting by dst: histogram -> single-block scan -> scatter
// ---------------------------------------------------------------------------
__global__ __launch_bounds__(256) void hist_kernel(
    const int* __restrict__ ei, int* __restrict__ deg, int E)
{
  const int e = (int)((unsigned)blockIdx.x * 256u + threadIdx.x);
  if (e < E) atomicAdd(deg + ei[E + e], 1);
}

__global__ __launch_bounds__(256) void scan_kernel(
    const int* __restrict__ deg, int* __restrict__ rowptr, int N)
{
  __shared__ int part[256];
  const int t = threadIdx.x;
  const int chunk = (N + 255) / 256;
  const int start = t * chunk;
  const int stop  = min(start + chunk, N);
  int sum = 0;
  for (int j = start; j < stop; ++j) sum += deg[j];
  part[t] = sum;
  __syncthreads();
  for (int off = 1; off < 256; off <<= 1) {
    int v = (t >= off) ? part[t - off] : 0;
    __syncthreads();
    part[t] += v;
    __syncthreads();
  }
  int base = (t == 0) ? 0 : part[t - 1];
  for (int j = start; j < stop; ++j) { rowptr[j] = base; base += deg[j]; }
  if (t == 255) rowptr[N] = part[255];
}

__global__ __launch_bounds__(256) void scatter_kernel(
    const int* __restrict__ ei, const int* __restrict__ rowptr,
    int* __restrict__ cursor, int* __restrict__ ssrc, int* __restrict__ sdst, int E)
{
  const int e = (int)((unsigned)blockIdx.x * 256u + threadIdx.x);
  if (e >= E) return;
  const int src = ei[e];
  const int d   = ei[E + e];
  const int p   = rowptr[d] + atomicAdd(cursor + d, 1);
  ssrc[p] = src;
  sdst[p] = d;
}

// ---------------------------------------------------------------------------
// Projection: p[i][h] = sum_k feat[i][k] * u[k][h].  One wave per node.
// ---------------------------------------------------------------------------
__global__ __launch_bounds__(256) void proj128_kernel(
    const bf16* __restrict__ x, const bf16* __restrict__ u,
    float4* __restrict__ p, int N)
{
  const int node = (int)(((unsigned)blockIdx.x * 256u + threadIdx.x) >> 6);
  if (node >= N) return;
  const int lane = threadIdx.x & 63;
  const unsigned xv = ((const unsigned*)(x + (size_t)node * 128))[lane];
  const float d0 = bflo(xv), d1 = bfhi(xv);
  const uint4 uv = *(const uint4*)(u + (size_t)lane * 8);
  float t0 = d0 * bflo(uv.x) + d1 * bflo(uv.z);
  float t1 = d0 * bfhi(uv.x) + d1 * bfhi(uv.z);
  float t2 = d0 * bflo(uv.y) + d1 * bflo(uv.w);
  float t3 = d0 * bfhi(uv.y) + d1 * bfhi(uv.w);
  #pragma unroll
  for (int off = 32; off > 0; off >>= 1) {
    t0 += __shfl_xor(t0, off);
    t1 += __shfl_xor(t1, off);
    t2 += __shfl_xor(t2, off);
    t3 += __shfl_xor(t3, off);
  }
  if (lane == 0) p[node] = make_float4(t0, t1, t2, t3);
}

__global__ __launch_bounds__(256) void proj256_kernel(
    const bf16* __restrict__ h, const bf16* __restrict__ u,
    float4* __restrict__ p, int N)
{
  const int node = (int)(((unsigned)blockIdx.x * 256u + threadIdx.x) >> 6);
  if (node >= N) return;
  const int lane = threadIdx.x & 63;
  const uint2 hv = *(const uint2*)(h + (size_t)node * 256 + lane * 4);
  const float d0 = bflo(hv.x), d1 = bfhi(hv.x);
  const float d2 = bflo(hv.y), d3 = bfhi(hv.y);
  const uint4 ua = *(const uint4*)(u + (size_t)lane * 16);
  const uint4 ub = *(const uint4*)(u + (size_t)lane * 16 + 8);
  float t0 = d0*bflo(ua.x) + d1*bflo(ua.z) + d2*bflo(ub.x) + d3*bflo(ub.z);
  float t1 = d0*bfhi(ua.x) + d1*bfhi(ua.z) + d2*bfhi(ub.x) + d3*bfhi(ub.z);
  float t2 = d0*bflo(ua.y) + d1*bflo(ua.w) + d2*bflo(ub.y) + d3*bflo(ub.w);
  float t3 = d0*bfhi(ua.y) + d1*bfhi(ua.w) + d2*bfhi(ub.y) + d3*bfhi(ub.w);
  #pragma unroll
  for (int off = 32; off > 0; off >>= 1) {
    t0 += __shfl_xor(t0, off);
    t1 += __shfl_xor(t1, off);
    t2 += __shfl_xor(t2, off);
    t3 += __shfl_xor(t3, off);
  }
  if (lane == 0) p[node] = make_float4(t0, t1, t2, t3);
}

// ---------------------------------------------------------------------------
// Pass A: per sorted edge, q = softmax(p[src] - p[dst] + c). Thread per edge.
// ---------------------------------------------------------------------------
__global__ __launch_bounds__(256) void passA_kernel(
    const float4* __restrict__ p, const int* __restrict__ ssrc,
    const int* __restrict__ sdst, const bf16* __restrict__ cvec,
    float4* __restrict__ qs, int E)
{
  const int e = (int)((unsigned)blockIdx.x * 256u + threadIdx.x);
  if (e >= E) return;
  const float4 ps = p[ssrc[e]];
  const float4 pd = p[sdst[e]];
  const float t0 = ps.x - pd.x + __bfloat162float(cvec[0]);
  const float t1 = ps.y - pd.y + __bfloat162float(cvec[1]);
  const float t2 = ps.z - pd.z + __bfloat162float(cvec[2]);
  const float t3 = ps.w - pd.w + __bfloat162float(cvec[3]);
  const float mx = fmaxf(fmaxf(t0, t1), fmaxf(t2, t3));
  const float e0 = __expf(t0 - mx), e1 = __expf(t1 - mx);
  const float e2 = __expf(t2 - mx), e3 = __expf(t3 - mx);
  const float inv = 1.f / (e0 + e1 + e2 + e3);
  qs[e] = make_float4(e0 * inv, e1 * inv, e2 * inv, e3 * inv);
}

// ---------------------------------------------------------------------------
// Pass B v4: one block per dst node. Lane owns 4 channels (16B dwordx4 of the
// fp8 head-interleaved y row); each of the 4 waves independently processes
// edges e ≡ wave (mod 4), unrolled x4 -> 4 independent 1KB-row gathers in
// flight. Cross-wave reduction through LDS, then fused epilogue.
// ---------------------------------------------------------------------------
#define PB_CHUNK 64

template<bool OUT_FLOAT, bool SKIP_FLOAT>
__global__ __launch_bounds__(256) void passB_kernel(
    const int* __restrict__ rowptr, const int* __restrict__ ssrc,
    const float4* __restrict__ qs, const unsigned char* __restrict__ y,
    const bf16* __restrict__ cvec, const bf16* __restrict__ bias,
    const float* __restrict__ skipf, const bf16* __restrict__ skipb,
    float* __restrict__ outf, bf16* __restrict__ outb)
{
  __shared__ int    s_off[PB_CHUNK];
  __shared__ float4 s_q[PB_CHUNK];
  __shared__ float  red[4][256];

  const int i   = blockIdx.x;
  const int t   = threadIdx.x;
  const int g   = t >> 6;       // wave id
  const int l   = t & 63;       // lane: channels 4l..4l+3
  const int beg = rowptr[i], end = rowptr[i + 1];
  const int deg = end - beg;

  f32x2 ap0 = {0.f, 0.f}, ap1 = {0.f, 0.f}, ap2 = {0.f, 0.f}, ap3 = {0.f, 0.f};

#define PB_BODY(EIDX)                                                          \
  {                                                                            \
    const int    off = s_off[EIDX];                                            \
    const float4 q   = s_q[EIDX];                                              \
    const uint4  v   = *(const uint4*)(y + (size_t)off + l * 16);              \
    f32x2 q01; q01.x = q.x; q01.y = q.y;                                       \
    f32x2 q23; q23.x = q.z; q23.y = q.w;                                       \
    ap0 += q01 * __builtin_amdgcn_cvt_pk_f32_fp8((int)v.x, false)              \
         + q23 * __builtin_amdgcn_cvt_pk_f32_fp8((int)v.x, true);              \
    ap1 += q01 * __builtin_amdgcn_cvt_pk_f32_fp8((int)v.y, false)              \
         + q23 * __builtin_amdgcn_cvt_pk_f32_fp8((int)v.y, true);              \
    ap2 += q01 * __builtin_amdgcn_cvt_pk_f32_fp8((int)v.z, false)              \
         + q23 * __builtin_amdgcn_cvt_pk_f32_fp8((int)v.z, true);              \
    ap3 += q01 * __builtin_amdgcn_cvt_pk_f32_fp8((int)v.w, false)              \
         + q23 * __builtin_amdgcn_cvt_pk_f32_fp8((int)v.w, true);              \
  }

  for (int c0 = 0; c0 < deg; c0 += PB_CHUNK) {
    const int cnt = min(PB_CHUNK, deg - c0);
    __syncthreads();
    if (t < cnt) {
      s_off[t] = ssrc[beg + c0 + t] << 10;   // byte offset of y row
      s_q[t]   = qs[beg + c0 + t];
    }
    __syncthreads();

    int e = g;
    for (; e + 12 < cnt; e += 16) {          // 4 independent gathers in flight
      PB_BODY(e) PB_BODY(e + 4) PB_BODY(e + 8) PB_BODY(e + 12)
    }
    for (; e < cnt; e += 4) PB_BODY(e)
  }
#undef PB_BODY

  // cross-wave reduction: red[g][channel]
  __syncthreads();
  {
    float4 r;
    r.x = ap0.x + ap0.y; r.y = ap1.x + ap1.y;
    r.z = ap2.x + ap2.y; r.w = ap3.x + ap3.y;
    *(float4*)&red[g][l * 4] = r;
  }
  __syncthreads();

  const int ch = t;
  float acc = red[0][ch] + red[1][ch] + red[2][ch] + red[3][ch];

  // self loop: q = softmax(c)
  const float c0 = __bfloat162float(cvec[0]), c1 = __bfloat162float(cvec[1]);
  const float c2 = __bfloat162float(cvec[2]), c3 = __bfloat162float(cvec[3]);
  const float mx = fmaxf(fmaxf(c0, c1), fmaxf(c2, c3));
  const float e0 = __expf(c0 - mx), e1 = __expf(c1 - mx);
  const float e2 = __expf(c2 - mx), e3 = __expf(c3 - mx);
  const float inv = 1.f / (e0 + e1 + e2 + e3);
  const unsigned vi = *(const unsigned*)(y + (size_t)i * 1024 + ch * 4);
  const f32x2 li  = __builtin_amdgcn_cvt_pk_f32_fp8((int)vi, false);
  const f32x2 hii = __builtin_amdgcn_cvt_pk_f32_fp8((int)vi, true);
  acc += (e0 * li.x + e1 * li.y + e2 * hii.x + e3 * hii.y) * inv;

  const int idx = i * 256 + ch;
  float v = acc / (float)(deg + 1) + __bfloat162float(bias[ch]);
  v += SKIP_FLOAT ? skipf[idx] : __bfloat162float(skipb[idx]);
  v = fmaxf(v, 0.f);
  if (OUT_FLOAT) outf[idx] = v;
  else           outb[idx] = __float2bfloat16(v);
}

// Output 1: edge_index values written as float32
__global__ __launch_bounds__(256) void edgecopy_kernel(
    const int* __restrict__ ei, float* __restrict__ out, int n)
{
  const int i = (int)((unsigned)blockIdx.x * 256u + threadIdx.x);
  if (i < n) out[i] = (float)ei[i];
}

extern "C" void kernel_launch(void* const* d_in, const int* in_sizes, int n_in,
                              void* d_out, int out_size, void* d_ws, size_t ws_size,
                              hipStream_t stream)
{
  const bf16* x   = (const bf16*)d_in[0];
  const int*  ei  = (const int*)d_in[1];
  const bf16* W0  = (const bf16*)d_in[2];
  const bf16* u0  = (const bf16*)d_in[3];
  const bf16* c0  = (const bf16*)d_in[4];
  const bf16* b0  = (const bf16*)d_in[5];
  const bf16* sW0 = (const bf16*)d_in[6];
  const bf16* sb0 = (const bf16*)d_in[7];
  const bf16* W1  = (const bf16*)d_in[8];
  const bf16* u1  = (const bf16*)d_in[9];
  const bf16* c1  = (const bf16*)d_in[10];
  const bf16* b1  = (const bf16*)d_in[11];

  const int N = in_sizes[0] / 128;   // 20000
  const int E = in_sizes[1] / 2;     // 320000

  // workspace layout (~64 MB)
  char* ws = (char*)d_ws;
  unsigned char* y = (unsigned char*)ws; ws += (size_t)N * 1024;        // fp8, head-interleaved
  float*  skip0  = (float*)ws;  ws += (size_t)N * 256 * sizeof(float);
  bf16*   h0     = (bf16*)ws;   ws += (size_t)N * 256 * sizeof(bf16);
  float4* qs     = (float4*)ws; ws += (size_t)E * sizeof(float4);
  float4* p      = (float4*)ws; ws += (size_t)N * sizeof(float4);
  int*    ssrc   = (int*)ws;    ws += (size_t)E * sizeof(int);
  int*    sdst   = (int*)ws;    ws += (size_t)E * sizeof(int);
  int*    deg    = (int*)ws;    ws += (size_t)N * sizeof(int);
  int*    cursor = (int*)ws;    ws += (size_t)N * sizeof(int);
  int*    rowptr = (int*)ws;    ws += ((size_t)N + 1) * sizeof(int);
  bf16*   Bt0    = (bf16*)ws;   ws += (size_t)1280 * 128 * sizeof(bf16); // [W0|sW0]^T
  bf16*   Bt1    = (bf16*)ws;   ws += (size_t)1024 * 256 * sizeof(bf16); // W1^T

  hipMemsetAsync(deg, 0, 2 * (size_t)N * sizeof(int), stream);  // deg + cursor

  const int eBlocks = (E + 255) / 256;
  const int nwBlocks = (N * 64 + 255) / 256;   // wave-per-node kernels
  const int mTiles  = (N + 127) / 128;

  // ---- weight transposes ----
  transpose_kernel<<<dim3(1024/32, 128/32), 256, 0, stream>>>(W0,  Bt0,               128, 1024);
  transpose_kernel<<<dim3( 256/32, 128/32), 256, 0, stream>>>(sW0, Bt0 + 1024 * 128,  128,  256);
  transpose_kernel<<<dim3(1024/32, 256/32), 256, 0, stream>>>(W1,  Bt1,               256, 1024);

  // ---- sort edges by dst ----
  hist_kernel<<<eBlocks, 256, 0, stream>>>(ei, deg, E);
  scan_kernel<<<1, 256, 0, stream>>>(deg, rowptr, N);
  scatter_kernel<<<eBlocks, 256, 0, stream>>>(ei, rowptr, cursor, ssrc, sdst, E);

  // ---- Block 0 ----
  proj128_kernel<<<nwBlocks, 256, 0, stream>>>(x, u0, p, N);
  gemm_mfma_kernel<<<dim3(mTiles, 10), 256, 0, stream>>>(
      x, Bt0, N, 128, y, 1024, skip0, sb0, 256);
  passA_kernel<<<eBlocks, 256, 0, stream>>>(p, ssrc, sdst, c0, qs, E);
  passB_kernel<false, true><<<N, 256, 0, stream>>>(rowptr, ssrc, qs, y, c0, b0,
                                                   skip0, nullptr, nullptr, h0);

  // ---- Block 1 ----
  proj256_kernel<<<nwBlocks, 256, 0, stream>>>(h0, u1, p, N);
  gemm_mfma_kernel<<<dim3(mTiles, 8), 256, 0, stream>>>(
      h0, Bt1, N, 256, y, 1024, nullptr, nullptr, 256);
  passA_kernel<<<eBlocks, 256, 0, stream>>>(p, ssrc, sdst, c1, qs, E);
  passB_kernel<true, false><<<N, 256, 0, stream>>>(rowptr, ssrc, qs, y, c1, b1,
                                                   nullptr, h0, (float*)d_out, nullptr);

  // ---- Output 1: edge_index ----
  edgecopy_kernel<<<(2 * E + 255) / 256, 256, 0, stream>>>(
      ei, (float*)d_out + (size_t)N * 256, 2 * E);
}